// Round 4
// baseline (237.588 us; speedup 1.0000x reference)
//
#include <hip/hip_runtime.h>

#define BS 256
#define THR 1024
#define EPB 8192          // edges per prep block (LDS-sorted)
#define BSHC 8            // 256 nodes per COARSE bucket
#define CAPC 8192         // fixed capacity per coarse-bucket span (~4096+pads expected, huge margin)
#define AST 68            // fp32 LDS row stride (16B aligned, 2-way bank alias only)
#define CAP 1024          // max (padded) edges per fine bucket staged in LDS
#define SRCMASK 0x0FFFFFFF
#define SRC20   0x000FFFFF

typedef __attribute__((ext_vector_type(8))) short bf16x8;
typedef __attribute__((ext_vector_type(4))) float f32x4;

__device__ inline unsigned bfpack2(float a, float b) {
    unsigned ua = __float_as_uint(a), ub = __float_as_uint(b);
    ua = (ua + 0x7fffu + ((ua >> 16) & 1u)) >> 16;
    ub = (ub + 0x7fffu + ((ub >> 16) & 1u)) >> 16;
    return ua | (ub << 16);
}
__device__ inline float lo16(unsigned u) { return __uint_as_float(u << 16); }
__device__ inline float hi16(unsigned u) { return __uint_as_float(u & 0xffff0000u); }
__device__ inline bf16x8 pack8(float4 a, float4 b) {
    union { unsigned u[4]; bf16x8 v; } r;
    r.u[0] = bfpack2(a.x, a.y); r.u[1] = bfpack2(a.z, a.w);
    r.u[2] = bfpack2(b.x, b.y); r.u[3] = bfpack2(b.z, b.w);
    return r.v;
}

// xb: ROW-MAJOR 64 bf16 = 128B/node (one cache line per gather). Row n is ZERO
// (pad sentinel). pk3 layout after refine: per coarse bucket, per-NODE runs padded
// to multiples of 8 with sentinel (n | (node&15)<<28); within a node, edges are
// sorted by src-group (src>>15) for cross-block L2 phase alignment (round-2: 79MB).
// pk3 bits 28..31 = node-WITHIN-fine (d&15) -- consumed by k_final2's accr index.

// ---------- ONE-PASS prep: ticketed bucket sort | x->bf16 | weight-frag pack ----------
__global__ __launch_bounds__(1024) void k_prep_all(const int* __restrict__ idx,
        int* __restrict__ curG, int* __restrict__ pk2, int E, int NBC, int nbs,
        const float* __restrict__ x, unsigned* __restrict__ xb, int total8, int nN,
        float* __restrict__ sarr,
        const float* __restrict__ W1l, const float* __restrict__ W1r,
        unsigned short* __restrict__ wfrag, int xblocks) {
    extern __shared__ int smem[];
    __shared__ int is64_s;
    int tid = threadIdx.x;
    int bid = blockIdx.x;

    if (bid < nbs) {
        int* pkL = smem;                                   // EPB ints
        unsigned short* binb = (unsigned short*)(smem + EPB);  // EPB ushorts
        int* hist  = (int*)(binb + EPB);                   // NBC
        int* gbase = hist + NBC;                           // NBC
        int* lcur  = gbase + NBC;                          // NBC
        for (int b = tid; b < NBC; b += THR) { hist[b] = 0; lcur[b] = 0; }
        if (tid < 64) {
            int v = idx[2 * tid + 1];
            unsigned long long bl = __ballot(v != 0);
            if (tid == 0) is64_s = (bl == 0ULL) ? 1 : 0;
        }
        __syncthreads();
        int is64 = is64_s;
        int base = bid * EPB;
        int ecnt = E - base; if (ecnt > EPB) ecnt = EPB;
#pragma unroll
        for (int j = 0; j < EPB / THR; j++) {
            int loc = j * THR + tid;
            if (loc < ecnt) {
                long e = base + loc;
                int s, d;
                if (is64) {
                    int2 sp = *(const int2*)(idx + 2 * e);
                    int2 dp = *(const int2*)(idx + 2L * E + 2 * e);
                    s = sp.x; d = dp.x;
                } else {
                    s = idx[e]; d = idx[(long)E + e];
                }
                pkL[loc] = s | ((d & 255) << 20);
                int bin = d >> BSHC;
                binb[loc] = (unsigned short)bin;
                atomicAdd(&hist[bin], 1);
            }
        }
        __syncthreads();
        for (int b = tid; b < NBC; b += THR) {
            int h = hist[b];
            gbase[b] = h ? atomicAdd(&curG[b * 16], h) : 0;
        }
        __syncthreads();
#pragma unroll
        for (int j = 0; j < EPB / THR; j++) {
            int loc = j * THR + tid;
            if (loc < ecnt) {
                int bin = binb[loc];
                int lpos = atomicAdd(&lcur[bin], 1);
                long gpos = (long)gbase[bin] + lpos;
                if (gpos < CAPC)             // overflow edges dropped; bucket flagged via curG
                    pk2[(size_t)bin * CAPC + gpos] = pkL[loc];
            }
        }
    } else if (bid < nbs + xblocks) {
        int i = (bid - nbs) * THR + tid;
        if (i < total8) {
            const float4 a = *(const float4*)(x + (size_t)i * 8);
            const float4 b = *(const float4*)(x + (size_t)i * 8 + 4);
            uint4 o;
            o.x = bfpack2(a.x, a.y); o.y = bfpack2(a.z, a.w);
            o.z = bfpack2(b.x, b.y); o.w = bfpack2(b.z, b.w);
            *(uint4*)(xb + (size_t)i * 4) = o;
        }
        if (bid == nbs) {   // zero sentinel row n + sarr[n]
            if (tid < 8) *(uint4*)(xb + (size_t)nN * 32 + tid * 4) = make_uint4(0, 0, 0, 0);
            if (tid == 8) sarr[nN] = 0.f;
        }
    } else {
        if (tid < 64) {
            int lane = tid;
            int nloc = lane & 15, quad = lane >> 4;
            for (int p = 0; p < 2; p++) {
                const float* W = p ? W1r : W1l;
                for (int jt = 0; jt < 4; jt++) {
                    for (int ks = 0; ks < 2; ks++) {
                        float v[8];
#pragma unroll
                        for (int i = 0; i < 8; i++) {
                            int k = ks * 32 + quad * 8 + i;
                            v[i] = W[k * 64 + jt * 16 + nloc];
                        }
                        bf16x8 f = pack8(make_float4(v[0], v[1], v[2], v[3]),
                                         make_float4(v[4], v[5], v[6], v[7]));
                        int slot = (p * 4 + jt) * 2 + ks;
                        *(bf16x8*)(wfrag + ((size_t)slot * 64 + lane) * 8) = f;
                    }
                }
            }
        }
    }
}

// ---------- refine: coarse span -> per-NODE padded runs, src-group ordered ----------
__global__ __launch_bounds__(1024) void k_refine(const int* __restrict__ pk2,
        const int* __restrict__ curG, int* __restrict__ fstart, int* __restrict__ fcnt,
        int* __restrict__ ncnt, int* __restrict__ pk3, int NBC, int n) {
    __shared__ int h4[1024];      // [node256][srcgrp4] histogram
    __shared__ int base4[1024];   // scatter cursors
    __shared__ int pb_s[256];     // padded base slot per node
    __shared__ int wsum_s[4];
    __shared__ int totpad_s;
    int tid = threadIdx.x;
    int B = blockIdx.x;
    int fill = curG[B * 16];
    if (fill > CAPC) {            // overflow (adversarial): flag for slow path
        if (tid < 16) fcnt[B * 16 + tid] = -1;
        return;
    }
    h4[tid] = 0;
    __syncthreads();
    size_t s0 = (size_t)B * CAPC;
    int vreg[CAPC / THR];         // fully unrolled -> registers
#pragma unroll
    for (int k = 0; k < CAPC / THR; k++) {
        int i = k * THR + tid;
        if (i < fill) {
            int p = pk2[s0 + i];
            vreg[k] = p;
            atomicAdd(&h4[(((((unsigned)p) >> 20) & 255) << 2) | ((p >> 15) & 3)], 1);
        }
    }
    __syncthreads();
    int incl = 0, pc = 0, cn = 0;
    if (tid < 256) {              // padded (mult-of-8) prefix over 256 nodes
        cn = h4[tid * 4] + h4[tid * 4 + 1] + h4[tid * 4 + 2] + h4[tid * 4 + 3];
        pc = (cn + 7) >> 3;
        incl = pc;
#pragma unroll
        for (int d = 1; d < 64; d <<= 1) {
            int y = __shfl_up(incl, d);
            if ((tid & 63) >= d) incl += y;
        }
        if ((tid & 63) == 63) wsum_s[tid >> 6] = incl;
    }
    __syncthreads();
    if (tid < 256) {
        int w = tid >> 6, woff = 0;
        for (int j = 0; j < w; j++) woff += wsum_s[j];
        int excl = incl - pc + woff;
        pb_s[tid] = excl << 3;
        if (tid == 255) totpad_s = (excl + pc) << 3;
    }
    __syncthreads();
    int totpad = totpad_s;
    if (totpad > CAPC) {          // pads wouldn't fit: flag (never for this input)
        if (tid < 16) fcnt[B * 16 + tid] = -1;
        return;
    }
    if (tid < 16) {
        int fs = pb_s[tid * 16];
        int fe = (tid == 15) ? totpad : pb_s[(tid + 1) * 16];
        fstart[B * 16 + tid] = (int)(s0 + fs);
        fcnt[B * 16 + tid] = fe - fs;
    }
    if (tid < 256) {
        int nd = B * 256 + tid;
        if (nd < n) ncnt[nd] = cn;
    }
    {   // scatter cursors: pb + within-node src-group prefix
        int nd = tid >> 2, g = tid & 3;
        int off = 0;
#pragma unroll
        for (int gg = 0; gg < 3; gg++) if (gg < g) off += h4[(nd << 2) | gg];
        base4[tid] = pb_s[nd] + off;
    }
    __syncthreads();
#pragma unroll
    for (int k = 0; k < CAPC / THR; k++) {
        int i = k * THR + tid;
        if (i < fill) {
            int p = vreg[k];
            int bin = (((((unsigned)p) >> 20) & 255) << 2) | ((p >> 15) & 3);
            int pos = atomicAdd(&base4[bin], 1);
            // keep src (bits 0..19) + node-WITHIN-fine (d&15, p bits 20..23) in 28..31
            pk3[s0 + pos] = (p & SRC20) | (((((unsigned)p) >> 20) & 15) << 28);
        }
    }
    if (tid < 256) {              // write pad sentinels (disjoint slots, no barrier)
        int pc8 = pc << 3;
        int padw = n | ((tid & 15) << 28);   // sentinel src + node-within-fine tag
        for (int k2 = cn; k2 < pc8; k2++)
            pk3[s0 + pb_s[tid] + k2] = padw;
    }
}

// ---------- FUSED: balanced chunk gather (no sort, no tails) + MFMA + epilogue ----------
__global__ __launch_bounds__(256) void k_agg_gemm(
        const unsigned short* __restrict__ xb, const int* __restrict__ pk3,
        const int* __restrict__ fstart, const int* __restrict__ fcnt,
        const int* __restrict__ ncnt,
        const unsigned short* __restrict__ wfrag,
        const float* __restrict__ b1, const float* __restrict__ W2l,
        const float* __restrict__ W2r,
        float* __restrict__ sarr, float* __restrict__ tarr,
        float* __restrict__ invdeg, int n,
        const int* __restrict__ idx, int E) {
    __shared__ int srcb[CAP];
    __shared__ unsigned short chn_s[CAP / 8];   // chunk -> node | (chunkidx<<4)
    __shared__ int pbase_s[16], rcnt_s[16];
    __shared__ float rinv_s[16];
    __shared__ int nch_s;
    __shared__ float agg_s[16 * AST];
    __shared__ float sred[4 * 16], tred[4 * 16];
    __shared__ int is64_s;

    int tid = threadIdx.x;
    int b = blockIdx.x;
    int grp = tid >> 4, l = tid & 15;
    int node = b * 16 + grp;
    int m = fcnt[b];
    const unsigned short* xbase = xb + l * 4;

    if (m >= 0) {
        if (tid < 16) {           // per-node metadata: padded prefix + chunk map
            int nd = b * 16 + tid;
            int cn = (nd < n) ? ncnt[nd] : 0;
            int pc = (cn + 7) >> 3;
            int incl = pc;
#pragma unroll
            for (int d = 1; d < 16; d <<= 1) {
                int y = __shfl_up(incl, d, 16);
                if (tid >= d) incl += y;
            }
            int excl = incl - pc;
            pbase_s[tid] = excl << 3;
            rcnt_s[tid] = cn;
            float iv = 1.0f / (float)(cn < 1 ? 1 : cn);
            rinv_s[tid] = iv;
            if (nd < n) invdeg[nd] = iv;
            if (m <= CAP) {
                for (int k = 0; k < pc; k++)
                    chn_s[excl + k] = (unsigned short)(tid | (k << 4));
            }
            if (tid == 15) nch_s = incl;
        }
        if (m <= CAP) {
            for (int i = tid; i < 16 * AST; i += 256) agg_s[i] = 0.f;
            int ebeg = fstart[b];
            for (int i = tid; i < m; i += 256)
                srcb[i] = __builtin_nontemporal_load(pk3 + ebeg + i);
            __syncthreads();
            int nch = nch_s;
            for (int c = grp; c < nch; c += 16) {
                int ce = chn_s[c];
                int nd = ce & 15;
                int base = pbase_s[nd] + ((ce >> 4) << 3);
                int j0 = srcb[base + 0] & SRCMASK, j1 = srcb[base + 1] & SRCMASK;
                int j2 = srcb[base + 2] & SRCMASK, j3 = srcb[base + 3] & SRCMASK;
                int j4 = srcb[base + 4] & SRCMASK, j5 = srcb[base + 5] & SRCMASK;
                int j6 = srcb[base + 6] & SRCMASK, j7 = srcb[base + 7] & SRCMASK;
                uint2 v0 = *(const uint2*)(xbase + (size_t)j0 * 64);
                uint2 v1 = *(const uint2*)(xbase + (size_t)j1 * 64);
                uint2 v2 = *(const uint2*)(xbase + (size_t)j2 * 64);
                uint2 v3 = *(const uint2*)(xbase + (size_t)j3 * 64);
                uint2 v4 = *(const uint2*)(xbase + (size_t)j4 * 64);
                uint2 v5 = *(const uint2*)(xbase + (size_t)j5 * 64);
                uint2 v6 = *(const uint2*)(xbase + (size_t)j6 * 64);
                uint2 v7 = *(const uint2*)(xbase + (size_t)j7 * 64);
                float f0 = lo16(v0.x) + lo16(v1.x) + lo16(v2.x) + lo16(v3.x)
                         + lo16(v4.x) + lo16(v5.x) + lo16(v6.x) + lo16(v7.x);
                float f1 = hi16(v0.x) + hi16(v1.x) + hi16(v2.x) + hi16(v3.x)
                         + hi16(v4.x) + hi16(v5.x) + hi16(v6.x) + hi16(v7.x);
                float f2 = lo16(v0.y) + lo16(v1.y) + lo16(v2.y) + lo16(v3.y)
                         + lo16(v4.y) + lo16(v5.y) + lo16(v6.y) + lo16(v7.y);
                float f3 = hi16(v0.y) + hi16(v1.y) + hi16(v2.y) + hi16(v3.y)
                         + hi16(v4.y) + hi16(v5.y) + hi16(v6.y) + hi16(v7.y);
                float* ap = agg_s + nd * AST + l * 4;
                atomicAdd(ap + 0, f0); atomicAdd(ap + 1, f1);
                atomicAdd(ap + 2, f2); atomicAdd(ap + 3, f3);
            }
            __syncthreads();
        } else {
            // rare big bucket: per-group padded walk straight from global
            __syncthreads();
            int cn = rcnt_s[grp];
            int pc8 = ((cn + 7) >> 3) << 3;
            int base = fstart[b] + pbase_s[grp];
            float f0 = 0.f, f1 = 0.f, f2 = 0.f, f3 = 0.f;
            for (int e = 0; e < pc8; e += 8) {
#pragma unroll
                for (int k = 0; k < 8; k++) {
                    int j = __builtin_nontemporal_load(pk3 + base + e + k) & SRCMASK;
                    uint2 v = *(const uint2*)(xbase + (size_t)j * 64);
                    f0 += lo16(v.x); f1 += hi16(v.x);
                    f2 += lo16(v.y); f3 += hi16(v.y);
                }
            }
            *(float4*)(agg_s + grp * AST + l * 4) = make_float4(f0, f1, f2, f3);
            __syncthreads();
        }
    } else {
        // flagged (span overflow): correct-but-slow direct scan of idx
        if (tid < 64) {
            int v = idx[2 * tid + 1];
            unsigned long long bl = __ballot(v != 0);
            if (tid == 0) is64_s = (bl == 0ULL) ? 1 : 0;
        }
        __syncthreads();
        int is64 = is64_s;
        float f0 = 0.f, f1 = 0.f, f2 = 0.f, f3 = 0.f;
        int cnt = 0;
        if (node < n) {
            for (long e = 0; e < E; e++) {
                int d = is64 ? idx[2L * E + 2 * e] : idx[(long)E + e];
                if (d == node) {
                    int s = is64 ? idx[2 * e] : idx[e];
                    cnt++;
                    uint2 v = *(const uint2*)(xbase + (size_t)s * 64);
                    f0 += lo16(v.x); f1 += hi16(v.x); f2 += lo16(v.y); f3 += hi16(v.y);
                }
            }
        }
        float iv = 1.0f / (float)(cnt < 1 ? 1 : cnt);
        if (l == 0) {
            rinv_s[grp] = iv;
            if (node < n) invdeg[node] = iv;
        }
        *(float4*)(agg_s + grp * AST + l * 4) = make_float4(f0, f1, f2, f3);
        __syncthreads();
    }

    // ---- epilogue: pack (x mean-inv) + MFMA + layer-2 partials ----
    int wave = tid >> 6;
    int lane = tid & 63;
    int nloc = lane & 15, quad = lane >> 4;

    float iv = rinv_s[nloc];
    const float* arow = agg_s + nloc * AST + quad * 8;
    float4 a0 = *(const float4*)(arow), a1 = *(const float4*)(arow + 4);
    float4 a2 = *(const float4*)(arow + 32), a3 = *(const float4*)(arow + 36);
    bf16x8 aA0 = pack8(make_float4(a0.x * iv, a0.y * iv, a0.z * iv, a0.w * iv),
                       make_float4(a1.x * iv, a1.y * iv, a1.z * iv, a1.w * iv));
    bf16x8 aA1 = pack8(make_float4(a2.x * iv, a2.y * iv, a2.z * iv, a2.w * iv),
                       make_float4(a3.x * iv, a3.y * iv, a3.z * iv, a3.w * iv));
    int node_a = b * 16 + nloc;
    int nc = node_a < n ? node_a : (n - 1);
    const unsigned short* xr = xb + (size_t)nc * 64;
    bf16x8 aX0 = *(const bf16x8*)(xr + quad * 8);
    bf16x8 aX1 = *(const bf16x8*)(xr + 32 + quad * 8);

    const bf16x8 bL0 = *(const bf16x8*)(wfrag + ((size_t)((0 * 4 + wave) * 2 + 0) * 64 + lane) * 8);
    const bf16x8 bL1 = *(const bf16x8*)(wfrag + ((size_t)((0 * 4 + wave) * 2 + 1) * 64 + lane) * 8);
    const bf16x8 bR0 = *(const bf16x8*)(wfrag + ((size_t)((1 * 4 + wave) * 2 + 0) * 64 + lane) * 8);
    const bf16x8 bR1 = *(const bf16x8*)(wfrag + ((size_t)((1 * 4 + wave) * 2 + 1) * 64 + lane) * 8);

    f32x4 acc = (f32x4){0.f, 0.f, 0.f, 0.f};
    acc = __builtin_amdgcn_mfma_f32_16x16x32_bf16(aA0, bL0, acc, 0, 0, 0);
    acc = __builtin_amdgcn_mfma_f32_16x16x32_bf16(aA1, bL1, acc, 0, 0, 0);
    acc = __builtin_amdgcn_mfma_f32_16x16x32_bf16(aX0, bR0, acc, 0, 0, 0);
    acc = __builtin_amdgcn_mfma_f32_16x16x32_bf16(aX1, bR1, acc, 0, 0, 0);

    int j = wave * 16 + nloc;
    float b1v = b1[j], w2lv = W2l[j], w2rv = W2r[j];
    float sp[4], tp[4];
#pragma unroll
    for (int r = 0; r < 4; r++) {
        float h = fmaxf(acc[r] + b1v, 0.f);
        sp[r] = h * w2lv;
        tp[r] = h * w2rv;
    }
#pragma unroll
    for (int mm = 1; mm < 16; mm <<= 1) {
#pragma unroll
        for (int r = 0; r < 4; r++) {
            sp[r] += __shfl_xor(sp[r], mm);
            tp[r] += __shfl_xor(tp[r], mm);
        }
    }
    if (nloc == 0) {
#pragma unroll
        for (int r = 0; r < 4; r++) {
            sred[wave * 16 + quad * 4 + r] = sp[r];
            tred[wave * 16 + quad * 4 + r] = tp[r];
        }
    }
    __syncthreads();
    if (tid < 16) {
        int nd = b * 16 + tid;
        if (nd < n) {
            sarr[nd] = sred[tid] + sred[16 + tid] + sred[32 + tid] + sred[48 + tid];
            tarr[nd] = tred[tid] + tred[16 + tid] + tred[32 + tid] + tred[48 + tid];
        }
    }
}

// ---------- per-fine-bucket layer-2 mean aggregation + output ----------
__global__ __launch_bounds__(256) void k_final2(const int* __restrict__ pk3,
        const int* __restrict__ fstart, const int* __restrict__ fcnt,
        const float* __restrict__ sarr, const float* __restrict__ tarr,
        const float* __restrict__ invdeg, const float* __restrict__ b2,
        float* __restrict__ out, int n,
        const int* __restrict__ idx, int E) {
    __shared__ float accr[16 * 8];
    __shared__ int is64_s;
    int tid = threadIdx.x;
    int b = blockIdx.x;
    int m = fcnt[b];
    if (tid < 128) accr[tid] = 0.f;
    __syncthreads();
    if (m >= 0) {
        int ebeg = fstart[b];
        int rep = tid & 7;
        for (int i = ebeg + tid; i < ebeg + m; i += 256) {
            int p = __builtin_nontemporal_load(pk3 + i);
            float s = sarr[p & SRCMASK];        // pads hit sarr[n] == 0
            atomicAdd(&accr[(((unsigned)p) >> 28) * 8 + rep], s);
        }
        __syncthreads();
        if (tid < 16) {
            int node = b * 16 + tid;
            if (node < n) {
                float a = 0.f;
#pragma unroll
                for (int r = 0; r < 8; r++) a += accr[tid * 8 + r];
                out[node] = a * invdeg[node] + b2[0] + tarr[node];
            }
        }
    } else {
        // flagged: slow direct scan
        if (tid < 64) {
            int v = idx[2 * tid + 1];
            unsigned long long bl = __ballot(v != 0);
            if (tid == 0) is64_s = (bl == 0ULL) ? 1 : 0;
        }
        __syncthreads();
        int is64 = is64_s;
        if (tid < 16) {
            int node = b * 16 + tid;
            if (node < n) {
                float a = 0.f;
                for (long e = 0; e < E; e++) {
                    int d = is64 ? idx[2L * E + 2 * e] : idx[(long)E + e];
                    if (d == node) {
                        int s = is64 ? idx[2 * e] : idx[e];
                        a += sarr[s];
                    }
                }
                out[node] = a * invdeg[node] + b2[0] + tarr[node];
            }
        }
    }
}

extern "C" void kernel_launch(void* const* d_in, const int* in_sizes, int n_in,
                              void* d_out, int out_size, void* d_ws, size_t ws_size,
                              hipStream_t stream) {
    const float* x   = (const float*)d_in[0];
    const int*   idx = (const int*)d_in[1];
    const float* W1l = (const float*)d_in[2];
    const float* b1  = (const float*)d_in[3];
    const float* W1r = (const float*)d_in[4];
    const float* W2l = (const float*)d_in[5];
    const float* b2  = (const float*)d_in[6];
    const float* W2r = (const float*)d_in[7];
    float* out = (float*)d_out;

    const int n = in_sizes[0] / 64;       // 100000
    const int E = in_sizes[1] / 2;        // 1600000
    const int NBC = (n + 255) >> BSHC;    // coarse buckets (256 nodes)
    const int NBF = NBC * 16;             // fine buckets (16 nodes)

    char* ws = (char*)d_ws;
    size_t off = 0;
    auto carve = [&](size_t bytes) {
        void* p = ws + off;
        off = (off + bytes + 255) & ~(size_t)255;
        return p;
    };
    float* sarr    = (float*)carve((size_t)(n + 1) * 4);    // +1: zero sentinel
    float* tarr    = (float*)carve((size_t)n * 4);
    float* invdeg  = (float*)carve((size_t)n * 4);
    int*   ncnt    = (int*)  carve((size_t)n * 4);
    int*   curG    = (int*)  carve((size_t)NBC * 64);        // 64B-padded cursors
    int*   fstart  = (int*)  carve((size_t)NBF * 4);
    int*   fcnt    = (int*)  carve((size_t)NBF * 4);
    unsigned short* wfrag = (unsigned short*)carve(16 * 64 * 8 * 2);
    int*   pk2  = (int*)carve((size_t)NBC * CAPC * 4);
    int*   pk3  = (int*)carve((size_t)NBC * CAPC * 4);
    unsigned short* xbu = (unsigned short*)carve((size_t)(n + 1) * 128);  // +1: zero row
    (void)ws_size; (void)n_in; (void)out_size;

    const int total8 = n * 8;
    const int xblocks = (total8 + THR - 1) / THR;
    const int nbs = (E + EPB - 1) / EPB;
    const size_t dynLds = (size_t)EPB * 6 + (size_t)NBC * 12;

    hipMemsetAsync(curG, 0, (size_t)NBC * 64, stream);
    k_prep_all<<<nbs + xblocks + 1, THR, dynLds, stream>>>(
        idx, curG, pk2, E, NBC, nbs, x, (unsigned*)xbu, total8, n, sarr, W1l, W1r, wfrag, xblocks);
    k_refine<<<NBC, THR, 0, stream>>>(pk2, curG, fstart, fcnt, ncnt, pk3, NBC, n);
    k_agg_gemm<<<NBF, BS, 0, stream>>>(xbu, pk3, fstart, fcnt, ncnt, wfrag, b1, W2l, W2r,
                                       sarr, tarr, invdeg, n, idx, E);
    k_final2<<<NBF, BS, 0, stream>>>(pk3, fstart, fcnt, sarr, tarr, invdeg, b2,
                                     out, n, idx, E);
}

// Round 5
// 166.502 us; speedup vs baseline: 1.4269x; 1.4269x over previous
//
#include <hip/hip_runtime.h>

#define BS 256
#define THR 1024
#define EPB 8192          // edges per prep block (LDS-sorted)
#define BSHC 8            // 256 nodes per COARSE bucket
#define CAPC 8192         // fixed capacity per coarse-bucket span (~4096+pads expected, huge margin)
#define AST 68            // fp32 LDS row stride (16B aligned, 2-way bank alias only)
#define CAP 1024          // max (padded) edges per fine bucket staged in LDS
#define SRCMASK 0x0FFFFFFF
#define SRC20   0x000FFFFF

typedef __attribute__((ext_vector_type(8))) short bf16x8;
typedef __attribute__((ext_vector_type(4))) float f32x4;

__device__ inline unsigned bfpack2(float a, float b) {
    unsigned ua = __float_as_uint(a), ub = __float_as_uint(b);
    ua = (ua + 0x7fffu + ((ua >> 16) & 1u)) >> 16;
    ub = (ub + 0x7fffu + ((ub >> 16) & 1u)) >> 16;
    return ua | (ub << 16);
}
__device__ inline float lo16(unsigned u) { return __uint_as_float(u << 16); }
__device__ inline float hi16(unsigned u) { return __uint_as_float(u & 0xffff0000u); }
__device__ inline bf16x8 pack8(float4 a, float4 b) {
    union { unsigned u[4]; bf16x8 v; } r;
    r.u[0] = bfpack2(a.x, a.y); r.u[1] = bfpack2(a.z, a.w);
    r.u[2] = bfpack2(b.x, b.y); r.u[3] = bfpack2(b.z, b.w);
    return r.v;
}

// xb: ROW-MAJOR 64 bf16 = 128B/node (one cache line per gather). Row n is ZERO
// (pad sentinel). pk3 layout after refine: per coarse bucket, per-NODE runs padded
// to multiples of 8 with sentinel (n | (node&15)<<28); within a node, edges are
// sorted by src-group (src>>15) for cross-block L2 phase alignment (round-2: 79MB).
// pk3 bits 28..31 = node-WITHIN-fine (d&15) -- consumed by k_final2's accr index.
// k_agg_gemm: REGISTER-accumulating per-group walk (round-2 core). Round-4 lesson:
// LDS atomics inside the gather loop serialize the DS queue and kill cross-iteration
// memory-level parallelism (44us -> 110us with identical VALU work) -- never again.

// ---------- ONE-PASS prep: ticketed bucket sort | x->bf16 | weight-frag pack ----------
__global__ __launch_bounds__(1024) void k_prep_all(const int* __restrict__ idx,
        int* __restrict__ curG, int* __restrict__ pk2, int E, int NBC, int nbs,
        const float* __restrict__ x, unsigned* __restrict__ xb, int total8, int nN,
        float* __restrict__ sarr,
        const float* __restrict__ W1l, const float* __restrict__ W1r,
        unsigned short* __restrict__ wfrag, int xblocks) {
    extern __shared__ int smem[];
    __shared__ int is64_s;
    int tid = threadIdx.x;
    int bid = blockIdx.x;

    if (bid < nbs) {
        int* pkL = smem;                                   // EPB ints
        unsigned short* binb = (unsigned short*)(smem + EPB);  // EPB ushorts
        int* hist  = (int*)(binb + EPB);                   // NBC
        int* gbase = hist + NBC;                           // NBC
        int* lcur  = gbase + NBC;                          // NBC
        for (int b = tid; b < NBC; b += THR) { hist[b] = 0; lcur[b] = 0; }
        if (tid < 64) {
            int v = idx[2 * tid + 1];
            unsigned long long bl = __ballot(v != 0);
            if (tid == 0) is64_s = (bl == 0ULL) ? 1 : 0;
        }
        __syncthreads();
        int is64 = is64_s;
        int base = bid * EPB;
        int ecnt = E - base; if (ecnt > EPB) ecnt = EPB;
#pragma unroll
        for (int j = 0; j < EPB / THR; j++) {
            int loc = j * THR + tid;
            if (loc < ecnt) {
                long e = base + loc;
                int s, d;
                if (is64) {
                    int2 sp = *(const int2*)(idx + 2 * e);
                    int2 dp = *(const int2*)(idx + 2L * E + 2 * e);
                    s = sp.x; d = dp.x;
                } else {
                    s = idx[e]; d = idx[(long)E + e];
                }
                pkL[loc] = s | ((d & 255) << 20);
                int bin = d >> BSHC;
                binb[loc] = (unsigned short)bin;
                atomicAdd(&hist[bin], 1);
            }
        }
        __syncthreads();
        for (int b = tid; b < NBC; b += THR) {
            int h = hist[b];
            gbase[b] = h ? atomicAdd(&curG[b * 16], h) : 0;
        }
        __syncthreads();
#pragma unroll
        for (int j = 0; j < EPB / THR; j++) {
            int loc = j * THR + tid;
            if (loc < ecnt) {
                int bin = binb[loc];
                int lpos = atomicAdd(&lcur[bin], 1);
                long gpos = (long)gbase[bin] + lpos;
                if (gpos < CAPC)             // overflow edges dropped; bucket flagged via curG
                    pk2[(size_t)bin * CAPC + gpos] = pkL[loc];
            }
        }
    } else if (bid < nbs + xblocks) {
        int i = (bid - nbs) * THR + tid;
        if (i < total8) {
            const float4 a = *(const float4*)(x + (size_t)i * 8);
            const float4 b = *(const float4*)(x + (size_t)i * 8 + 4);
            uint4 o;
            o.x = bfpack2(a.x, a.y); o.y = bfpack2(a.z, a.w);
            o.z = bfpack2(b.x, b.y); o.w = bfpack2(b.z, b.w);
            *(uint4*)(xb + (size_t)i * 4) = o;
        }
        if (bid == nbs) {   // zero sentinel row n + sarr[n]
            if (tid < 8) *(uint4*)(xb + (size_t)nN * 32 + tid * 4) = make_uint4(0, 0, 0, 0);
            if (tid == 8) sarr[nN] = 0.f;
        }
    } else {
        if (tid < 64) {
            int lane = tid;
            int nloc = lane & 15, quad = lane >> 4;
            for (int p = 0; p < 2; p++) {
                const float* W = p ? W1r : W1l;
                for (int jt = 0; jt < 4; jt++) {
                    for (int ks = 0; ks < 2; ks++) {
                        float v[8];
#pragma unroll
                        for (int i = 0; i < 8; i++) {
                            int k = ks * 32 + quad * 8 + i;
                            v[i] = W[k * 64 + jt * 16 + nloc];
                        }
                        bf16x8 f = pack8(make_float4(v[0], v[1], v[2], v[3]),
                                         make_float4(v[4], v[5], v[6], v[7]));
                        int slot = (p * 4 + jt) * 2 + ks;
                        *(bf16x8*)(wfrag + ((size_t)slot * 64 + lane) * 8) = f;
                    }
                }
            }
        }
    }
}

// ---------- refine: coarse span -> per-NODE padded runs, src-group ordered ----------
__global__ __launch_bounds__(1024) void k_refine(const int* __restrict__ pk2,
        const int* __restrict__ curG, int* __restrict__ fstart, int* __restrict__ fcnt,
        int* __restrict__ ncnt, int* __restrict__ pk3, int NBC, int n) {
    __shared__ int h4[1024];      // [node256][srcgrp4] histogram
    __shared__ int base4[1024];   // scatter cursors
    __shared__ int pb_s[256];     // padded base slot per node
    __shared__ int wsum_s[4];
    __shared__ int totpad_s;
    int tid = threadIdx.x;
    int B = blockIdx.x;
    int fill = curG[B * 16];
    if (fill > CAPC) {            // overflow (adversarial): flag for slow path
        if (tid < 16) fcnt[B * 16 + tid] = -1;
        return;
    }
    h4[tid] = 0;
    __syncthreads();
    size_t s0 = (size_t)B * CAPC;
    int vreg[CAPC / THR];         // fully unrolled -> registers
#pragma unroll
    for (int k = 0; k < CAPC / THR; k++) {
        int i = k * THR + tid;
        if (i < fill) {
            int p = pk2[s0 + i];
            vreg[k] = p;
            atomicAdd(&h4[(((((unsigned)p) >> 20) & 255) << 2) | ((p >> 15) & 3)], 1);
        }
    }
    __syncthreads();
    int incl = 0, pc = 0, cn = 0;
    if (tid < 256) {              // padded (mult-of-8) prefix over 256 nodes
        cn = h4[tid * 4] + h4[tid * 4 + 1] + h4[tid * 4 + 2] + h4[tid * 4 + 3];
        pc = (cn + 7) >> 3;
        incl = pc;
#pragma unroll
        for (int d = 1; d < 64; d <<= 1) {
            int y = __shfl_up(incl, d);
            if ((tid & 63) >= d) incl += y;
        }
        if ((tid & 63) == 63) wsum_s[tid >> 6] = incl;
    }
    __syncthreads();
    if (tid < 256) {
        int w = tid >> 6, woff = 0;
        for (int j = 0; j < w; j++) woff += wsum_s[j];
        int excl = incl - pc + woff;
        pb_s[tid] = excl << 3;
        if (tid == 255) totpad_s = (excl + pc) << 3;
    }
    __syncthreads();
    int totpad = totpad_s;
    if (totpad > CAPC) {          // pads wouldn't fit: flag (never for this input)
        if (tid < 16) fcnt[B * 16 + tid] = -1;
        return;
    }
    if (tid < 16) {
        int fs = pb_s[tid * 16];
        int fe = (tid == 15) ? totpad : pb_s[(tid + 1) * 16];
        fstart[B * 16 + tid] = (int)(s0 + fs);
        fcnt[B * 16 + tid] = fe - fs;
    }
    if (tid < 256) {
        int nd = B * 256 + tid;
        if (nd < n) ncnt[nd] = cn;
    }
    {   // scatter cursors: pb + within-node src-group prefix
        int nd = tid >> 2, g = tid & 3;
        int off = 0;
#pragma unroll
        for (int gg = 0; gg < 3; gg++) if (gg < g) off += h4[(nd << 2) | gg];
        base4[tid] = pb_s[nd] + off;
    }
    __syncthreads();
#pragma unroll
    for (int k = 0; k < CAPC / THR; k++) {
        int i = k * THR + tid;
        if (i < fill) {
            int p = vreg[k];
            int bin = (((((unsigned)p) >> 20) & 255) << 2) | ((p >> 15) & 3);
            int pos = atomicAdd(&base4[bin], 1);
            // keep src (bits 0..19) + node-WITHIN-fine (d&15, p bits 20..23) in 28..31
            pk3[s0 + pos] = (p & SRC20) | (((((unsigned)p) >> 20) & 15) << 28);
        }
    }
    if (tid < 256) {              // write pad sentinels (disjoint slots, no barrier)
        int pc8 = pc << 3;
        int padw = n | ((tid & 15) << 28);   // sentinel src + node-within-fine tag
        for (int k2 = cn; k2 < pc8; k2++)
            pk3[s0 + pb_s[tid] + k2] = padw;
    }
}

// ---------- FUSED: per-group register-walk over padded runs + MFMA + epilogue ----------
__global__ __launch_bounds__(256) void k_agg_gemm(
        const unsigned short* __restrict__ xb, const int* __restrict__ pk3,
        const int* __restrict__ fstart, const int* __restrict__ fcnt,
        const int* __restrict__ ncnt,
        const unsigned short* __restrict__ wfrag,
        const float* __restrict__ b1, const float* __restrict__ W2l,
        const float* __restrict__ W2r,
        float* __restrict__ sarr, float* __restrict__ tarr,
        float* __restrict__ invdeg, int n,
        const int* __restrict__ idx, int E) {
    __shared__ int srcb[CAP];
    __shared__ int pbase_s[16];
    __shared__ int rcnt_s[16];
    __shared__ float rinv_s[16];
    __shared__ float agg_s[16 * AST];
    __shared__ float sred[4 * 16], tred[4 * 16];
    __shared__ int is64_s;

    int tid = threadIdx.x;
    int b = blockIdx.x;
    int grp = tid >> 4, l = tid & 15;
    int node = b * 16 + grp;
    int m = fcnt[b];
    const unsigned short* xbase = xb + l * 4;

    float f0 = 0.f, f1 = 0.f, f2 = 0.f, f3 = 0.f;

    if (m >= 0) {
        if (tid < 16) {           // per-node metadata: padded prefix within the span
            int nd = b * 16 + tid;
            int cn = (nd < n) ? ncnt[nd] : 0;
            int pc = (cn + 7) >> 3;
            int incl = pc;
#pragma unroll
            for (int d = 1; d < 16; d <<= 1) {
                int y = __shfl_up(incl, d, 16);
                if (tid >= d) incl += y;
            }
            pbase_s[tid] = (incl - pc) << 3;
            rcnt_s[tid] = cn;
            float iv = 1.0f / (float)(cn < 1 ? 1 : cn);
            rinv_s[tid] = iv;
            if (nd < n) invdeg[nd] = iv;
        }
        if (m <= CAP) {
            int ebeg = fstart[b];
            for (int i = tid; i < m; i += 256)
                srcb[i] = __builtin_nontemporal_load(pk3 + ebeg + i);
            __syncthreads();
            int cn = rcnt_s[grp];
            int pc8 = ((cn + 7) >> 3) << 3;       // padded: no tail, no predication
            int s0 = pbase_s[grp];
            for (int e = 0; e < pc8; e += 8) {
                int j0 = srcb[s0+e+0] & SRCMASK, j1 = srcb[s0+e+1] & SRCMASK;
                int j2 = srcb[s0+e+2] & SRCMASK, j3 = srcb[s0+e+3] & SRCMASK;
                int j4 = srcb[s0+e+4] & SRCMASK, j5 = srcb[s0+e+5] & SRCMASK;
                int j6 = srcb[s0+e+6] & SRCMASK, j7 = srcb[s0+e+7] & SRCMASK;
                uint2 v0 = *(const uint2*)(xbase + (size_t)j0 * 64);
                uint2 v1 = *(const uint2*)(xbase + (size_t)j1 * 64);
                uint2 v2 = *(const uint2*)(xbase + (size_t)j2 * 64);
                uint2 v3 = *(const uint2*)(xbase + (size_t)j3 * 64);
                uint2 v4 = *(const uint2*)(xbase + (size_t)j4 * 64);
                uint2 v5 = *(const uint2*)(xbase + (size_t)j5 * 64);
                uint2 v6 = *(const uint2*)(xbase + (size_t)j6 * 64);
                uint2 v7 = *(const uint2*)(xbase + (size_t)j7 * 64);
                f0 += lo16(v0.x) + lo16(v1.x) + lo16(v2.x) + lo16(v3.x)
                    + lo16(v4.x) + lo16(v5.x) + lo16(v6.x) + lo16(v7.x);
                f1 += hi16(v0.x) + hi16(v1.x) + hi16(v2.x) + hi16(v3.x)
                    + hi16(v4.x) + hi16(v5.x) + hi16(v6.x) + hi16(v7.x);
                f2 += lo16(v0.y) + lo16(v1.y) + lo16(v2.y) + lo16(v3.y)
                    + lo16(v4.y) + lo16(v5.y) + lo16(v6.y) + lo16(v7.y);
                f3 += hi16(v0.y) + hi16(v1.y) + hi16(v2.y) + hi16(v3.y)
                    + hi16(v4.y) + hi16(v5.y) + hi16(v6.y) + hi16(v7.y);
            }
        } else {
            // rare big bucket: per-group padded walk straight from global
            __syncthreads();
            int cn = rcnt_s[grp];
            int pc8 = ((cn + 7) >> 3) << 3;
            int base = fstart[b] + pbase_s[grp];
            for (int e = 0; e < pc8; e += 8) {
#pragma unroll
                for (int k = 0; k < 8; k++) {
                    int j = __builtin_nontemporal_load(pk3 + base + e + k) & SRCMASK;
                    uint2 v = *(const uint2*)(xbase + (size_t)j * 64);
                    f0 += lo16(v.x); f1 += hi16(v.x);
                    f2 += lo16(v.y); f3 += hi16(v.y);
                }
            }
        }
    } else {
        // flagged (span overflow): correct-but-slow direct scan of idx
        if (tid < 64) {
            int v = idx[2 * tid + 1];
            unsigned long long bl = __ballot(v != 0);
            if (tid == 0) is64_s = (bl == 0ULL) ? 1 : 0;
        }
        __syncthreads();
        int is64 = is64_s;
        int cnt = 0;
        if (node < n) {
            for (long e = 0; e < E; e++) {
                int d = is64 ? idx[2L * E + 2 * e] : idx[(long)E + e];
                if (d == node) {
                    int s = is64 ? idx[2 * e] : idx[e];
                    cnt++;
                    uint2 v = *(const uint2*)(xbase + (size_t)s * 64);
                    f0 += lo16(v.x); f1 += hi16(v.x); f2 += lo16(v.y); f3 += hi16(v.y);
                }
            }
        }
        float iv = 1.0f / (float)(cnt < 1 ? 1 : cnt);
        if (l == 0) {
            rinv_s[grp] = iv;
            if (node < n) invdeg[node] = iv;
        }
    }
    *(float4*)(agg_s + grp * AST + l * 4) = make_float4(f0, f1, f2, f3);
    __syncthreads();

    // ---- epilogue: pack (x mean-inv) + MFMA + layer-2 partials ----
    int wave = tid >> 6;
    int lane = tid & 63;
    int nloc = lane & 15, quad = lane >> 4;

    float iv = rinv_s[nloc];
    const float* arow = agg_s + nloc * AST + quad * 8;
    float4 a0 = *(const float4*)(arow), a1 = *(const float4*)(arow + 4);
    float4 a2 = *(const float4*)(arow + 32), a3 = *(const float4*)(arow + 36);
    bf16x8 aA0 = pack8(make_float4(a0.x * iv, a0.y * iv, a0.z * iv, a0.w * iv),
                       make_float4(a1.x * iv, a1.y * iv, a1.z * iv, a1.w * iv));
    bf16x8 aA1 = pack8(make_float4(a2.x * iv, a2.y * iv, a2.z * iv, a2.w * iv),
                       make_float4(a3.x * iv, a3.y * iv, a3.z * iv, a3.w * iv));
    int node_a = b * 16 + nloc;
    int nc = node_a < n ? node_a : (n - 1);
    const unsigned short* xr = xb + (size_t)nc * 64;
    bf16x8 aX0 = *(const bf16x8*)(xr + quad * 8);
    bf16x8 aX1 = *(const bf16x8*)(xr + 32 + quad * 8);

    const bf16x8 bL0 = *(const bf16x8*)(wfrag + ((size_t)((0 * 4 + wave) * 2 + 0) * 64 + lane) * 8);
    const bf16x8 bL1 = *(const bf16x8*)(wfrag + ((size_t)((0 * 4 + wave) * 2 + 1) * 64 + lane) * 8);
    const bf16x8 bR0 = *(const bf16x8*)(wfrag + ((size_t)((1 * 4 + wave) * 2 + 0) * 64 + lane) * 8);
    const bf16x8 bR1 = *(const bf16x8*)(wfrag + ((size_t)((1 * 4 + wave) * 2 + 1) * 64 + lane) * 8);

    f32x4 acc = (f32x4){0.f, 0.f, 0.f, 0.f};
    acc = __builtin_amdgcn_mfma_f32_16x16x32_bf16(aA0, bL0, acc, 0, 0, 0);
    acc = __builtin_amdgcn_mfma_f32_16x16x32_bf16(aA1, bL1, acc, 0, 0, 0);
    acc = __builtin_amdgcn_mfma_f32_16x16x32_bf16(aX0, bR0, acc, 0, 0, 0);
    acc = __builtin_amdgcn_mfma_f32_16x16x32_bf16(aX1, bR1, acc, 0, 0, 0);

    int j = wave * 16 + nloc;
    float b1v = b1[j], w2lv = W2l[j], w2rv = W2r[j];
    float sp[4], tp[4];
#pragma unroll
    for (int r = 0; r < 4; r++) {
        float h = fmaxf(acc[r] + b1v, 0.f);
        sp[r] = h * w2lv;
        tp[r] = h * w2rv;
    }
#pragma unroll
    for (int mm = 1; mm < 16; mm <<= 1) {
#pragma unroll
        for (int r = 0; r < 4; r++) {
            sp[r] += __shfl_xor(sp[r], mm);
            tp[r] += __shfl_xor(tp[r], mm);
        }
    }
    if (nloc == 0) {
#pragma unroll
        for (int r = 0; r < 4; r++) {
            sred[wave * 16 + quad * 4 + r] = sp[r];
            tred[wave * 16 + quad * 4 + r] = tp[r];
        }
    }
    __syncthreads();
    if (tid < 16) {
        int nd = b * 16 + tid;
        if (nd < n) {
            sarr[nd] = sred[tid] + sred[16 + tid] + sred[32 + tid] + sred[48 + tid];
            tarr[nd] = tred[tid] + tred[16 + tid] + tred[32 + tid] + tred[48 + tid];
        }
    }
}

// ---------- per-fine-bucket layer-2 mean aggregation + output ----------
__global__ __launch_bounds__(256) void k_final2(const int* __restrict__ pk3,
        const int* __restrict__ fstart, const int* __restrict__ fcnt,
        const float* __restrict__ sarr, const float* __restrict__ tarr,
        const float* __restrict__ invdeg, const float* __restrict__ b2,
        float* __restrict__ out, int n,
        const int* __restrict__ idx, int E) {
    __shared__ float accr[16 * 8];
    __shared__ int is64_s;
    int tid = threadIdx.x;
    int b = blockIdx.x;
    int m = fcnt[b];
    if (tid < 128) accr[tid] = 0.f;
    __syncthreads();
    if (m >= 0) {
        int ebeg = fstart[b];
        int rep = tid & 7;
        for (int i = ebeg + tid; i < ebeg + m; i += 256) {
            int p = __builtin_nontemporal_load(pk3 + i);
            float s = sarr[p & SRCMASK];        // pads hit sarr[n] == 0
            atomicAdd(&accr[(((unsigned)p) >> 28) * 8 + rep], s);
        }
        __syncthreads();
        if (tid < 16) {
            int node = b * 16 + tid;
            if (node < n) {
                float a = 0.f;
#pragma unroll
                for (int r = 0; r < 8; r++) a += accr[tid * 8 + r];
                out[node] = a * invdeg[node] + b2[0] + tarr[node];
            }
        }
    } else {
        // flagged: slow direct scan
        if (tid < 64) {
            int v = idx[2 * tid + 1];
            unsigned long long bl = __ballot(v != 0);
            if (tid == 0) is64_s = (bl == 0ULL) ? 1 : 0;
        }
        __syncthreads();
        int is64 = is64_s;
        if (tid < 16) {
            int node = b * 16 + tid;
            if (node < n) {
                float a = 0.f;
                for (long e = 0; e < E; e++) {
                    int d = is64 ? idx[2L * E + 2 * e] : idx[(long)E + e];
                    if (d == node) {
                        int s = is64 ? idx[2 * e] : idx[e];
                        a += sarr[s];
                    }
                }
                out[node] = a * invdeg[node] + b2[0] + tarr[node];
            }
        }
    }
}

extern "C" void kernel_launch(void* const* d_in, const int* in_sizes, int n_in,
                              void* d_out, int out_size, void* d_ws, size_t ws_size,
                              hipStream_t stream) {
    const float* x   = (const float*)d_in[0];
    const int*   idx = (const int*)d_in[1];
    const float* W1l = (const float*)d_in[2];
    const float* b1  = (const float*)d_in[3];
    const float* W1r = (const float*)d_in[4];
    const float* W2l = (const float*)d_in[5];
    const float* b2  = (const float*)d_in[6];
    const float* W2r = (const float*)d_in[7];
    float* out = (float*)d_out;

    const int n = in_sizes[0] / 64;       // 100000
    const int E = in_sizes[1] / 2;        // 1600000
    const int NBC = (n + 255) >> BSHC;    // coarse buckets (256 nodes)
    const int NBF = NBC * 16;             // fine buckets (16 nodes)

    char* ws = (char*)d_ws;
    size_t off = 0;
    auto carve = [&](size_t bytes) {
        void* p = ws + off;
        off = (off + bytes + 255) & ~(size_t)255;
        return p;
    };
    float* sarr    = (float*)carve((size_t)(n + 1) * 4);    // +1: zero sentinel
    float* tarr    = (float*)carve((size_t)n * 4);
    float* invdeg  = (float*)carve((size_t)n * 4);
    int*   ncnt    = (int*)  carve((size_t)n * 4);
    int*   curG    = (int*)  carve((size_t)NBC * 64);        // 64B-padded cursors
    int*   fstart  = (int*)  carve((size_t)NBF * 4);
    int*   fcnt    = (int*)  carve((size_t)NBF * 4);
    unsigned short* wfrag = (unsigned short*)carve(16 * 64 * 8 * 2);
    int*   pk2  = (int*)carve((size_t)NBC * CAPC * 4);
    int*   pk3  = (int*)carve((size_t)NBC * CAPC * 4);
    unsigned short* xbu = (unsigned short*)carve((size_t)(n + 1) * 128);  // +1: zero row
    (void)ws_size; (void)n_in; (void)out_size;

    const int total8 = n * 8;
    const int xblocks = (total8 + THR - 1) / THR;
    const int nbs = (E + EPB - 1) / EPB;
    const size_t dynLds = (size_t)EPB * 6 + (size_t)NBC * 12;

    hipMemsetAsync(curG, 0, (size_t)NBC * 64, stream);
    k_prep_all<<<nbs + xblocks + 1, THR, dynLds, stream>>>(
        idx, curG, pk2, E, NBC, nbs, x, (unsigned*)xbu, total8, n, sarr, W1l, W1r, wfrag, xblocks);
    k_refine<<<NBC, THR, 0, stream>>>(pk2, curG, fstart, fcnt, ncnt, pk3, NBC, n);
    k_agg_gemm<<<NBF, BS, 0, stream>>>(xbu, pk3, fstart, fcnt, ncnt, wfrag, b1, W2l, W2r,
                                       sarr, tarr, invdeg, n, idx, E);
    k_final2<<<NBF, BS, 0, stream>>>(pk3, fstart, fcnt, sarr, tarr, invdeg, b2,
                                     out, n, idx, E);
}

// Round 6
// 165.466 us; speedup vs baseline: 1.4359x; 1.0063x over previous
//
#include <hip/hip_runtime.h>

#define BS 256
#define THR 1024
#define EPB 8192          // edges per prep block (LDS-sorted)
#define BSHC 8            // 256 nodes per COARSE bucket
#define CAPC 8192         // fixed capacity per coarse-bucket span (~4096+pads expected, huge margin)
#define ASTH 72           // f16 LDS row stride (144B, 16B aligned, 2-way bank alias only)
#define CAP 1024          // max (padded) edges per fine bucket staged in LDS
#define SRCMASK 0x0FFFFFFF
#define SRC20   0x000FFFFF

typedef __attribute__((ext_vector_type(2))) _Float16 h2;
typedef __attribute__((ext_vector_type(8))) _Float16 half8;
typedef __attribute__((ext_vector_type(2))) float f32x2;
typedef __attribute__((ext_vector_type(4))) float f32x4;

__device__ inline unsigned h2bits(h2 a) { union { h2 h; unsigned u; } x; x.h = a; return x.u; }
__device__ inline h2 bitsh2(unsigned u) { union { h2 h; unsigned u; } x; x.u = u; return x.h; }

// xb: ROW-MAJOR 64 f16 = 128B/node (one cache line per gather). Row n is ZERO
// (pad sentinel). pk3: per coarse bucket, per-NODE runs padded to mult-of-8 with
// sentinel (n | (node&15)<<28); within a node, edges sorted by src-group (src>>15)
// for cross-block L2 phase alignment (round-2: 79MB fetch).
// Round-5 lesson: agg's floor is the per-edge unpack+add VALU and VMEM issue, not
// bookkeeping. f16 pipeline: v_pk_add_f16 accumulate (4x less VALU than bf16
// unpack+f32 add) + uint4 16B/lane gather (2 edges per load instruction).

// ---------- ONE-PASS prep: ticketed bucket sort | x->f16 | weight-frag pack ----------
__global__ __launch_bounds__(1024) void k_prep_all(const int* __restrict__ idx,
        int* __restrict__ curG, int* __restrict__ pk2, int E, int NBC, int nbs,
        const float* __restrict__ x, unsigned* __restrict__ xb, int total8, int nN,
        float* __restrict__ sarr,
        const float* __restrict__ W1l, const float* __restrict__ W1r,
        unsigned short* __restrict__ wfrag, int xblocks) {
    extern __shared__ int smem[];
    __shared__ int is64_s;
    int tid = threadIdx.x;
    int bid = blockIdx.x;

    if (bid < nbs) {
        int* pkL = smem;                                   // EPB ints
        unsigned short* binb = (unsigned short*)(smem + EPB);  // EPB ushorts
        int* hist  = (int*)(binb + EPB);                   // NBC
        int* gbase = hist + NBC;                           // NBC
        int* lcur  = gbase + NBC;                          // NBC
        for (int b = tid; b < NBC; b += THR) { hist[b] = 0; lcur[b] = 0; }
        if (tid < 64) {
            int v = idx[2 * tid + 1];
            unsigned long long bl = __ballot(v != 0);
            if (tid == 0) is64_s = (bl == 0ULL) ? 1 : 0;
        }
        __syncthreads();
        int is64 = is64_s;
        int base = bid * EPB;
        int ecnt = E - base; if (ecnt > EPB) ecnt = EPB;
#pragma unroll
        for (int j = 0; j < EPB / THR; j++) {
            int loc = j * THR + tid;
            if (loc < ecnt) {
                long e = base + loc;
                int s, d;
                if (is64) {
                    int2 sp = *(const int2*)(idx + 2 * e);
                    int2 dp = *(const int2*)(idx + 2L * E + 2 * e);
                    s = sp.x; d = dp.x;
                } else {
                    s = idx[e]; d = idx[(long)E + e];
                }
                pkL[loc] = s | ((d & 255) << 20);
                int bin = d >> BSHC;
                binb[loc] = (unsigned short)bin;
                atomicAdd(&hist[bin], 1);
            }
        }
        __syncthreads();
        for (int b = tid; b < NBC; b += THR) {
            int h = hist[b];
            gbase[b] = h ? atomicAdd(&curG[b * 16], h) : 0;
        }
        __syncthreads();
#pragma unroll
        for (int j = 0; j < EPB / THR; j++) {
            int loc = j * THR + tid;
            if (loc < ecnt) {
                int bin = binb[loc];
                int lpos = atomicAdd(&lcur[bin], 1);
                long gpos = (long)gbase[bin] + lpos;
                if (gpos < CAPC)             // overflow edges dropped; bucket flagged via curG
                    pk2[(size_t)bin * CAPC + gpos] = pkL[loc];
            }
        }
    } else if (bid < nbs + xblocks) {
        int i = (bid - nbs) * THR + tid;
        if (i < total8) {
            const float4 a = *(const float4*)(x + (size_t)i * 8);
            const float4 b = *(const float4*)(x + (size_t)i * 8 + 4);
            half8 o;
            o[0] = (_Float16)a.x; o[1] = (_Float16)a.y;
            o[2] = (_Float16)a.z; o[3] = (_Float16)a.w;
            o[4] = (_Float16)b.x; o[5] = (_Float16)b.y;
            o[6] = (_Float16)b.z; o[7] = (_Float16)b.w;
            *(half8*)((unsigned short*)xb + (size_t)i * 8) = o;
        }
        if (bid == nbs) {   // zero sentinel row n + sarr[n]
            if (tid < 8) *(uint4*)(xb + (size_t)nN * 32 + tid * 4) = make_uint4(0, 0, 0, 0);
            if (tid == 8) sarr[nN] = 0.f;
        }
    } else {
        if (tid < 64) {
            int lane = tid;
            int nloc = lane & 15, quad = lane >> 4;
            for (int p = 0; p < 2; p++) {
                const float* W = p ? W1r : W1l;
                for (int jt = 0; jt < 4; jt++) {
                    for (int ks = 0; ks < 2; ks++) {
                        half8 f;
#pragma unroll
                        for (int i = 0; i < 8; i++) {
                            int k = ks * 32 + quad * 8 + i;
                            f[i] = (_Float16)W[k * 64 + jt * 16 + nloc];
                        }
                        int slot = (p * 4 + jt) * 2 + ks;
                        *(half8*)(wfrag + ((size_t)slot * 64 + lane) * 8) = f;
                    }
                }
            }
        }
    }
}

// ---------- refine: coarse span -> per-NODE padded runs, src-group ordered ----------
__global__ __launch_bounds__(1024) void k_refine(const int* __restrict__ pk2,
        const int* __restrict__ curG, int* __restrict__ fstart, int* __restrict__ fcnt,
        int* __restrict__ ncnt, int* __restrict__ pk3, int NBC, int n) {
    __shared__ int h4[1024];      // [node256][srcgrp4] histogram
    __shared__ int base4[1024];   // scatter cursors
    __shared__ int pb_s[256];     // padded base slot per node
    __shared__ int wsum_s[4];
    __shared__ int totpad_s;
    int tid = threadIdx.x;
    int B = blockIdx.x;
    int fill = curG[B * 16];
    if (fill > CAPC) {            // overflow (adversarial): flag for slow path
        if (tid < 16) fcnt[B * 16 + tid] = -1;
        return;
    }
    h4[tid] = 0;
    __syncthreads();
    size_t s0 = (size_t)B * CAPC;
    int vreg[CAPC / THR];         // fully unrolled -> registers
#pragma unroll
    for (int k = 0; k < CAPC / THR; k++) {
        int i = k * THR + tid;
        if (i < fill) {
            int p = pk2[s0 + i];
            vreg[k] = p;
            atomicAdd(&h4[(((((unsigned)p) >> 20) & 255) << 2) | ((p >> 15) & 3)], 1);
        }
    }
    __syncthreads();
    int incl = 0, pc = 0, cn = 0;
    if (tid < 256) {              // padded (mult-of-8) prefix over 256 nodes
        cn = h4[tid * 4] + h4[tid * 4 + 1] + h4[tid * 4 + 2] + h4[tid * 4 + 3];
        pc = (cn + 7) >> 3;
        incl = pc;
#pragma unroll
        for (int d = 1; d < 64; d <<= 1) {
            int y = __shfl_up(incl, d);
            if ((tid & 63) >= d) incl += y;
        }
        if ((tid & 63) == 63) wsum_s[tid >> 6] = incl;
    }
    __syncthreads();
    if (tid < 256) {
        int w = tid >> 6, woff = 0;
        for (int j = 0; j < w; j++) woff += wsum_s[j];
        int excl = incl - pc + woff;
        pb_s[tid] = excl << 3;
        if (tid == 255) totpad_s = (excl + pc) << 3;
    }
    __syncthreads();
    int totpad = totpad_s;
    if (totpad > CAPC) {          // pads wouldn't fit: flag (never for this input)
        if (tid < 16) fcnt[B * 16 + tid] = -1;
        return;
    }
    if (tid < 16) {
        int fs = pb_s[tid * 16];
        int fe = (tid == 15) ? totpad : pb_s[(tid + 1) * 16];
        fstart[B * 16 + tid] = (int)(s0 + fs);
        fcnt[B * 16 + tid] = fe - fs;
    }
    if (tid < 256) {
        int nd = B * 256 + tid;
        if (nd < n) ncnt[nd] = cn;
    }
    {   // scatter cursors: pb + within-node src-group prefix
        int nd = tid >> 2, g = tid & 3;
        int off = 0;
#pragma unroll
        for (int gg = 0; gg < 3; gg++) if (gg < g) off += h4[(nd << 2) | gg];
        base4[tid] = pb_s[nd] + off;
    }
    __syncthreads();
#pragma unroll
    for (int k = 0; k < CAPC / THR; k++) {
        int i = k * THR + tid;
        if (i < fill) {
            int p = vreg[k];
            int bin = (((((unsigned)p) >> 20) & 255) << 2) | ((p >> 15) & 3);
            int pos = atomicAdd(&base4[bin], 1);
            // keep src (bits 0..19) + node-WITHIN-fine (d&15, p bits 20..23) in 28..31
            pk3[s0 + pos] = (p & SRC20) | (((((unsigned)p) >> 20) & 15) << 28);
        }
    }
    if (tid < 256) {              // write pad sentinels (disjoint slots, no barrier)
        int pc8 = pc << 3;
        int padw = n | ((tid & 15) << 28);   // sentinel src + node-within-fine tag
        for (int k2 = cn; k2 < pc8; k2++)
            pk3[s0 + pb_s[tid] + k2] = padw;
    }
}

// ---------- FUSED: f16 pk_add gather over padded runs + f16 MFMA + epilogue ----------
__global__ __launch_bounds__(256) void k_agg_gemm(
        const unsigned short* __restrict__ xb, const int* __restrict__ pk3,
        const int* __restrict__ fstart, const int* __restrict__ fcnt,
        const int* __restrict__ ncnt,
        const unsigned short* __restrict__ wfrag,
        const float* __restrict__ b1, const float* __restrict__ W2l,
        const float* __restrict__ W2r,
        float* __restrict__ sarr, float* __restrict__ tarr,
        float* __restrict__ invdeg, int n,
        const int* __restrict__ idx, int E) {
    __shared__ int srcb[CAP];
    __shared__ int pbase_s[16];
    __shared__ int rcnt_s[16];
    __shared__ float rinv_s[16];
    __shared__ unsigned short aggh[16 * ASTH];   // f16 mean-agg rows
    __shared__ float sred[4 * 16], tred[4 * 16];
    __shared__ int is64_s;

    int tid = threadIdx.x;
    int b = blockIdx.x;
    int grp = tid >> 4, l = tid & 15;
    int node = b * 16 + grp;
    int m = fcnt[b];
    const char* xB = (const char*)xb;
    int sub = (l >> 3) & 1;                  // edge parity within the pair
    size_t qo = (size_t)(l & 7) << 4;        // 16B feature chunk (feats (l&7)*8..+7)

    if (m >= 0) {
        if (tid < 16) {           // per-node metadata: padded prefix within the span
            int nd = b * 16 + tid;
            int cn = (nd < n) ? ncnt[nd] : 0;
            int pc = (cn + 7) >> 3;
            int incl = pc;
#pragma unroll
            for (int d = 1; d < 16; d <<= 1) {
                int y = __shfl_up(incl, d, 16);
                if (tid >= d) incl += y;
            }
            pbase_s[tid] = (incl - pc) << 3;
            rcnt_s[tid] = cn;
            float iv = 1.0f / (float)(cn < 1 ? 1 : cn);
            rinv_s[tid] = iv;
            if (nd < n) invdeg[nd] = iv;
        }
        if (m <= CAP) {
            int ebeg = fstart[b];
            for (int i = tid; i < m; i += 256)
                srcb[i] = __builtin_nontemporal_load(pk3 + ebeg + i);
            __syncthreads();
            int cn = rcnt_s[grp];
            int pc8 = ((cn + 7) >> 3) << 3;       // padded: no tail, no predication
            int s0 = pbase_s[grp];
            h2 a0 = {0, 0}, a1 = {0, 0}, a2 = {0, 0}, a3 = {0, 0};
            for (int e = 0; e < pc8; e += 8) {
                int j0 = srcb[s0 + e + 0 + sub] & SRCMASK;
                int j1 = srcb[s0 + e + 2 + sub] & SRCMASK;
                int j2 = srcb[s0 + e + 4 + sub] & SRCMASK;
                int j3 = srcb[s0 + e + 6 + sub] & SRCMASK;
                uint4 v0 = *(const uint4*)(xB + ((size_t)j0 << 7) + qo);
                uint4 v1 = *(const uint4*)(xB + ((size_t)j1 << 7) + qo);
                uint4 v2 = *(const uint4*)(xB + ((size_t)j2 << 7) + qo);
                uint4 v3 = *(const uint4*)(xB + ((size_t)j3 << 7) + qo);
                a0 = a0 + (bitsh2(v0.x) + bitsh2(v1.x)) + (bitsh2(v2.x) + bitsh2(v3.x));
                a1 = a1 + (bitsh2(v0.y) + bitsh2(v1.y)) + (bitsh2(v2.y) + bitsh2(v3.y));
                a2 = a2 + (bitsh2(v0.z) + bitsh2(v1.z)) + (bitsh2(v2.z) + bitsh2(v3.z));
                a3 = a3 + (bitsh2(v0.w) + bitsh2(v1.w)) + (bitsh2(v2.w) + bitsh2(v3.w));
            }
            // merge the two parity lanes (l ^ 8) then mean-scale in f32
            a0 = a0 + bitsh2((unsigned)__shfl_xor((int)h2bits(a0), 8));
            a1 = a1 + bitsh2((unsigned)__shfl_xor((int)h2bits(a1), 8));
            a2 = a2 + bitsh2((unsigned)__shfl_xor((int)h2bits(a2), 8));
            a3 = a3 + bitsh2((unsigned)__shfl_xor((int)h2bits(a3), 8));
            float inv = rinv_s[grp];
            f32x2 g0 = __builtin_convertvector(a0, f32x2) * inv;
            f32x2 g1 = __builtin_convertvector(a1, f32x2) * inv;
            f32x2 g2 = __builtin_convertvector(a2, f32x2) * inv;
            f32x2 g3 = __builtin_convertvector(a3, f32x2) * inv;
            if (l < 8) {
                union { h2 h[4]; uint4 u; } ou;
                ou.h[0] = __builtin_convertvector(g0, h2);
                ou.h[1] = __builtin_convertvector(g1, h2);
                ou.h[2] = __builtin_convertvector(g2, h2);
                ou.h[3] = __builtin_convertvector(g3, h2);
                *(uint4*)(aggh + grp * ASTH + l * 8) = ou.u;
            }
        } else {
            // rare big bucket: per-group padded walk straight from global
            __syncthreads();
            int cn = rcnt_s[grp];
            int pc8 = ((cn + 7) >> 3) << 3;
            int base = fstart[b] + pbase_s[grp];
            h2 a0 = {0, 0}, a1 = {0, 0}, a2 = {0, 0}, a3 = {0, 0};
            for (int e = 0; e < pc8; e += 8) {
#pragma unroll
                for (int k = 0; k < 8; k++) {
                    int j = __builtin_nontemporal_load(pk3 + base + e + k) & SRCMASK;
                    uint4 v = *(const uint4*)(xB + ((size_t)j << 7) + qo);
                    a0 = a0 + bitsh2(v.x); a1 = a1 + bitsh2(v.y);
                    a2 = a2 + bitsh2(v.z); a3 = a3 + bitsh2(v.w);
                }
            }
            float inv = rinv_s[grp];       // all 16 lanes scanned all edges: no merge
            f32x2 g0 = __builtin_convertvector(a0, f32x2) * inv;
            f32x2 g1 = __builtin_convertvector(a1, f32x2) * inv;
            f32x2 g2 = __builtin_convertvector(a2, f32x2) * inv;
            f32x2 g3 = __builtin_convertvector(a3, f32x2) * inv;
            if (l < 8) {
                union { h2 h[4]; uint4 u; } ou;
                ou.h[0] = __builtin_convertvector(g0, h2);
                ou.h[1] = __builtin_convertvector(g1, h2);
                ou.h[2] = __builtin_convertvector(g2, h2);
                ou.h[3] = __builtin_convertvector(g3, h2);
                *(uint4*)(aggh + grp * ASTH + l * 8) = ou.u;
            }
        }
    } else {
        // flagged (span overflow): correct-but-slow direct scan of idx
        if (tid < 64) {
            int v = idx[2 * tid + 1];
            unsigned long long bl = __ballot(v != 0);
            if (tid == 0) is64_s = (bl == 0ULL) ? 1 : 0;
        }
        __syncthreads();
        int is64 = is64_s;
        h2 a0 = {0, 0}, a1 = {0, 0}, a2 = {0, 0}, a3 = {0, 0};
        int cnt = 0;
        if (node < n) {
            for (long e = 0; e < E; e++) {
                int d = is64 ? idx[2L * E + 2 * e] : idx[(long)E + e];
                if (d == node) {
                    int s = is64 ? idx[2 * e] : idx[e];
                    cnt++;
                    uint4 v = *(const uint4*)(xB + ((size_t)s << 7) + qo);
                    a0 = a0 + bitsh2(v.x); a1 = a1 + bitsh2(v.y);
                    a2 = a2 + bitsh2(v.z); a3 = a3 + bitsh2(v.w);
                }
            }
        }
        float iv = 1.0f / (float)(cnt < 1 ? 1 : cnt);
        if (l == 0 && node < n) invdeg[node] = iv;
        f32x2 g0 = __builtin_convertvector(a0, f32x2) * iv;
        f32x2 g1 = __builtin_convertvector(a1, f32x2) * iv;
        f32x2 g2 = __builtin_convertvector(a2, f32x2) * iv;
        f32x2 g3 = __builtin_convertvector(a3, f32x2) * iv;
        if (l < 8) {
            union { h2 h[4]; uint4 u; } ou;
            ou.h[0] = __builtin_convertvector(g0, h2);
            ou.h[1] = __builtin_convertvector(g1, h2);
            ou.h[2] = __builtin_convertvector(g2, h2);
            ou.h[3] = __builtin_convertvector(g3, h2);
            *(uint4*)(aggh + grp * ASTH + l * 8) = ou.u;
        }
    }
    __syncthreads();

    // ---- epilogue: f16 MFMA + layer-2 partials ----
    int wave = tid >> 6;
    int lane = tid & 63;
    int nloc = lane & 15, quad = lane >> 4;

    const unsigned short* ar = aggh + nloc * ASTH + quad * 8;
    half8 aA0 = *(const half8*)ar;
    half8 aA1 = *(const half8*)(ar + 32);
    int node_a = b * 16 + nloc;
    int nc = node_a < n ? node_a : (n - 1);
    const unsigned short* xr = xb + (size_t)nc * 64;
    half8 aX0 = *(const half8*)(xr + quad * 8);
    half8 aX1 = *(const half8*)(xr + 32 + quad * 8);

    const half8 bL0 = *(const half8*)(wfrag + ((size_t)((0 * 4 + wave) * 2 + 0) * 64 + lane) * 8);
    const half8 bL1 = *(const half8*)(wfrag + ((size_t)((0 * 4 + wave) * 2 + 1) * 64 + lane) * 8);
    const half8 bR0 = *(const half8*)(wfrag + ((size_t)((1 * 4 + wave) * 2 + 0) * 64 + lane) * 8);
    const half8 bR1 = *(const half8*)(wfrag + ((size_t)((1 * 4 + wave) * 2 + 1) * 64 + lane) * 8);

    f32x4 acc = (f32x4){0.f, 0.f, 0.f, 0.f};
    acc = __builtin_amdgcn_mfma_f32_16x16x32_f16(aA0, bL0, acc, 0, 0, 0);
    acc = __builtin_amdgcn_mfma_f32_16x16x32_f16(aA1, bL1, acc, 0, 0, 0);
    acc = __builtin_amdgcn_mfma_f32_16x16x32_f16(aX0, bR0, acc, 0, 0, 0);
    acc = __builtin_amdgcn_mfma_f32_16x16x32_f16(aX1, bR1, acc, 0, 0, 0);

    int j = wave * 16 + nloc;
    float b1v = b1[j], w2lv = W2l[j], w2rv = W2r[j];
    float sp[4], tp[4];
#pragma unroll
    for (int r = 0; r < 4; r++) {
        float h = fmaxf(acc[r] + b1v, 0.f);
        sp[r] = h * w2lv;
        tp[r] = h * w2rv;
    }
#pragma unroll
    for (int mm = 1; mm < 16; mm <<= 1) {
#pragma unroll
        for (int r = 0; r < 4; r++) {
            sp[r] += __shfl_xor(sp[r], mm);
            tp[r] += __shfl_xor(tp[r], mm);
        }
    }
    if (nloc == 0) {
#pragma unroll
        for (int r = 0; r < 4; r++) {
            sred[wave * 16 + quad * 4 + r] = sp[r];
            tred[wave * 16 + quad * 4 + r] = tp[r];
        }
    }
    __syncthreads();
    if (tid < 16) {
        int nd = b * 16 + tid;
        if (nd < n) {
            sarr[nd] = sred[tid] + sred[16 + tid] + sred[32 + tid] + sred[48 + tid];
            tarr[nd] = tred[tid] + tred[16 + tid] + tred[32 + tid] + tred[48 + tid];
        }
    }
}

// ---------- per-fine-bucket layer-2 mean aggregation + output ----------
__global__ __launch_bounds__(256) void k_final2(const int* __restrict__ pk3,
        const int* __restrict__ fstart, const int* __restrict__ fcnt,
        const float* __restrict__ sarr, const float* __restrict__ tarr,
        const float* __restrict__ invdeg, const float* __restrict__ b2,
        float* __restrict__ out, int n,
        const int* __restrict__ idx, int E) {
    __shared__ float accr[16 * 8];
    __shared__ int is64_s;
    int tid = threadIdx.x;
    int b = blockIdx.x;
    int m = fcnt[b];
    if (tid < 128) accr[tid] = 0.f;
    __syncthreads();
    if (m >= 0) {
        int ebeg = fstart[b];
        int rep = tid & 7;
        for (int i = ebeg + tid; i < ebeg + m; i += 256) {
            int p = __builtin_nontemporal_load(pk3 + i);
            float s = sarr[p & SRCMASK];        // pads hit sarr[n] == 0
            atomicAdd(&accr[(((unsigned)p) >> 28) * 8 + rep], s);
        }
        __syncthreads();
        if (tid < 16) {
            int node = b * 16 + tid;
            if (node < n) {
                float a = 0.f;
#pragma unroll
                for (int r = 0; r < 8; r++) a += accr[tid * 8 + r];
                out[node] = a * invdeg[node] + b2[0] + tarr[node];
            }
        }
    } else {
        // flagged: slow direct scan
        if (tid < 64) {
            int v = idx[2 * tid + 1];
            unsigned long long bl = __ballot(v != 0);
            if (tid == 0) is64_s = (bl == 0ULL) ? 1 : 0;
        }
        __syncthreads();
        int is64 = is64_s;
        if (tid < 16) {
            int node = b * 16 + tid;
            if (node < n) {
                float a = 0.f;
                for (long e = 0; e < E; e++) {
                    int d = is64 ? idx[2L * E + 2 * e] : idx[(long)E + e];
                    if (d == node) {
                        int s = is64 ? idx[2 * e] : idx[e];
                        a += sarr[s];
                    }
                }
                out[node] = a * invdeg[node] + b2[0] + tarr[node];
            }
        }
    }
}

extern "C" void kernel_launch(void* const* d_in, const int* in_sizes, int n_in,
                              void* d_out, int out_size, void* d_ws, size_t ws_size,
                              hipStream_t stream) {
    const float* x   = (const float*)d_in[0];
    const int*   idx = (const int*)d_in[1];
    const float* W1l = (const float*)d_in[2];
    const float* b1  = (const float*)d_in[3];
    const float* W1r = (const float*)d_in[4];
    const float* W2l = (const float*)d_in[5];
    const float* b2  = (const float*)d_in[6];
    const float* W2r = (const float*)d_in[7];
    float* out = (float*)d_out;

    const int n = in_sizes[0] / 64;       // 100000
    const int E = in_sizes[1] / 2;        // 1600000
    const int NBC = (n + 255) >> BSHC;    // coarse buckets (256 nodes)
    const int NBF = NBC * 16;             // fine buckets (16 nodes)

    char* ws = (char*)d_ws;
    size_t off = 0;
    auto carve = [&](size_t bytes) {
        void* p = ws + off;
        off = (off + bytes + 255) & ~(size_t)255;
        return p;
    };
    float* sarr    = (float*)carve((size_t)(n + 1) * 4);    // +1: zero sentinel
    float* tarr    = (float*)carve((size_t)n * 4);
    float* invdeg  = (float*)carve((size_t)n * 4);
    int*   ncnt    = (int*)  carve((size_t)n * 4);
    int*   curG    = (int*)  carve((size_t)NBC * 64);        // 64B-padded cursors
    int*   fstart  = (int*)  carve((size_t)NBF * 4);
    int*   fcnt    = (int*)  carve((size_t)NBF * 4);
    unsigned short* wfrag = (unsigned short*)carve(16 * 64 * 8 * 2);
    int*   pk2  = (int*)carve((size_t)NBC * CAPC * 4);
    int*   pk3  = (int*)carve((size_t)NBC * CAPC * 4);
    unsigned short* xbu = (unsigned short*)carve((size_t)(n + 1) * 128);  // +1: zero row
    (void)ws_size; (void)n_in; (void)out_size;

    const int total8 = n * 8;
    const int xblocks = (total8 + THR - 1) / THR;
    const int nbs = (E + EPB - 1) / EPB;
    const size_t dynLds = (size_t)EPB * 6 + (size_t)NBC * 12;

    hipMemsetAsync(curG, 0, (size_t)NBC * 64, stream);
    k_prep_all<<<nbs + xblocks + 1, THR, dynLds, stream>>>(
        idx, curG, pk2, E, NBC, nbs, x, (unsigned*)xbu, total8, n, sarr, W1l, W1r, wfrag, xblocks);
    k_refine<<<NBC, THR, 0, stream>>>(pk2, curG, fstart, fcnt, ncnt, pk3, NBC, n);
    k_agg_gemm<<<NBF, BS, 0, stream>>>(xbu, pk3, fstart, fcnt, ncnt, wfrag, b1, W2l, W2r,
                                       sarr, tarr, invdeg, n, idx, E);
    k_final2<<<NBF, BS, 0, stream>>>(pk3, fstart, fcnt, sarr, tarr, invdeg, b2,
                                     out, n, idx, E);
}

// Round 7
// 164.522 us; speedup vs baseline: 1.4441x; 1.0057x over previous
//
#include <hip/hip_runtime.h>

#define BS 256
#define THR 1024
#define EPB 8192          // edges per prep block (LDS-sorted)
#define BSHC 8            // 256 nodes per COARSE bucket
#define CAPC 8192         // fixed capacity per coarse-bucket span (~4096+pads expected, huge margin)
#define ASTH 72           // f16 LDS row stride (144B, 16B aligned, 2-way bank alias only)
#define CAP 1024          // max (padded) edges per fine bucket staged in LDS
#define SRCMASK 0x0FFFFFFF
#define SRC20   0x000FFFFF

typedef __attribute__((ext_vector_type(2))) _Float16 h2;
typedef __attribute__((ext_vector_type(8))) _Float16 half8;
typedef __attribute__((ext_vector_type(2))) float f32x2;
typedef __attribute__((ext_vector_type(4))) float f32x4;

__device__ inline unsigned h2bits(h2 a) { union { h2 h; unsigned u; } x; x.h = a; return x.u; }
__device__ inline h2 bitsh2(unsigned u) { union { h2 h; unsigned u; } x; x.u = u; return x.h; }

// xb: ROW-MAJOR 64 f16 = 128B/node (one cache line per gather). Row n is ZERO
// (pad sentinel). pk3: per coarse bucket, per-NODE runs padded to mult-of-8 with
// sentinel (n | (node&15)<<28); within a node, edges sorted by src-group (src>>15)
// for cross-block L2 phase alignment (round-2: 79MB fetch).
// Round-6 lesson: agg is invariant to traffic (2.6x), VALU (2x), instr count (2x)
// -> the limiter is per-iteration latency exposure (vmcnt(0) each 8 edges).
// This round: 2-deep manual software pipeline (issue next 4 loads BEFORE
// accumulating current 4) = T14 issue-early/consume-late.

// ---------- ONE-PASS prep: ticketed bucket sort | x->f16 | weight-frag pack ----------
__global__ __launch_bounds__(1024) void k_prep_all(const int* __restrict__ idx,
        int* __restrict__ curG, int* __restrict__ pk2, int E, int NBC, int nbs,
        const float* __restrict__ x, unsigned* __restrict__ xb, int total8, int nN,
        float* __restrict__ sarr,
        const float* __restrict__ W1l, const float* __restrict__ W1r,
        unsigned short* __restrict__ wfrag, int xblocks) {
    extern __shared__ int smem[];
    __shared__ int is64_s;
    int tid = threadIdx.x;
    int bid = blockIdx.x;

    if (bid < nbs) {
        int* pkL = smem;                                   // EPB ints
        unsigned short* binb = (unsigned short*)(smem + EPB);  // EPB ushorts
        int* hist  = (int*)(binb + EPB);                   // NBC
        int* gbase = hist + NBC;                           // NBC
        int* lcur  = gbase + NBC;                          // NBC
        for (int b = tid; b < NBC; b += THR) { hist[b] = 0; lcur[b] = 0; }
        if (tid < 64) {
            int v = idx[2 * tid + 1];
            unsigned long long bl = __ballot(v != 0);
            if (tid == 0) is64_s = (bl == 0ULL) ? 1 : 0;
        }
        __syncthreads();
        int is64 = is64_s;
        int base = bid * EPB;
        int ecnt = E - base; if (ecnt > EPB) ecnt = EPB;
#pragma unroll
        for (int j = 0; j < EPB / THR; j++) {
            int loc = j * THR + tid;
            if (loc < ecnt) {
                long e = base + loc;
                int s, d;
                if (is64) {
                    int2 sp = *(const int2*)(idx + 2 * e);
                    int2 dp = *(const int2*)(idx + 2L * E + 2 * e);
                    s = sp.x; d = dp.x;
                } else {
                    s = idx[e]; d = idx[(long)E + e];
                }
                pkL[loc] = s | ((d & 255) << 20);
                int bin = d >> BSHC;
                binb[loc] = (unsigned short)bin;
                atomicAdd(&hist[bin], 1);
            }
        }
        __syncthreads();
        for (int b = tid; b < NBC; b += THR) {
            int h = hist[b];
            gbase[b] = h ? atomicAdd(&curG[b * 16], h) : 0;
        }
        __syncthreads();
#pragma unroll
        for (int j = 0; j < EPB / THR; j++) {
            int loc = j * THR + tid;
            if (loc < ecnt) {
                int bin = binb[loc];
                int lpos = atomicAdd(&lcur[bin], 1);
                long gpos = (long)gbase[bin] + lpos;
                if (gpos < CAPC)             // overflow edges dropped; bucket flagged via curG
                    pk2[(size_t)bin * CAPC + gpos] = pkL[loc];
            }
        }
    } else if (bid < nbs + xblocks) {
        int i = (bid - nbs) * THR + tid;
        if (i < total8) {
            const float4 a = *(const float4*)(x + (size_t)i * 8);
            const float4 b = *(const float4*)(x + (size_t)i * 8 + 4);
            half8 o;
            o[0] = (_Float16)a.x; o[1] = (_Float16)a.y;
            o[2] = (_Float16)a.z; o[3] = (_Float16)a.w;
            o[4] = (_Float16)b.x; o[5] = (_Float16)b.y;
            o[6] = (_Float16)b.z; o[7] = (_Float16)b.w;
            *(half8*)((unsigned short*)xb + (size_t)i * 8) = o;
        }
        if (bid == nbs) {   // zero sentinel row n + sarr[n]
            if (tid < 8) *(uint4*)(xb + (size_t)nN * 32 + tid * 4) = make_uint4(0, 0, 0, 0);
            if (tid == 8) sarr[nN] = 0.f;
        }
    } else {
        if (tid < 64) {
            int lane = tid;
            int nloc = lane & 15, quad = lane >> 4;
            for (int p = 0; p < 2; p++) {
                const float* W = p ? W1r : W1l;
                for (int jt = 0; jt < 4; jt++) {
                    for (int ks = 0; ks < 2; ks++) {
                        half8 f;
#pragma unroll
                        for (int i = 0; i < 8; i++) {
                            int k = ks * 32 + quad * 8 + i;
                            f[i] = (_Float16)W[k * 64 + jt * 16 + nloc];
                        }
                        int slot = (p * 4 + jt) * 2 + ks;
                        *(half8*)(wfrag + ((size_t)slot * 64 + lane) * 8) = f;
                    }
                }
            }
        }
    }
}

// ---------- refine: coarse span -> per-NODE padded runs, src-group ordered ----------
__global__ __launch_bounds__(1024) void k_refine(const int* __restrict__ pk2,
        const int* __restrict__ curG, int* __restrict__ fstart, int* __restrict__ fcnt,
        int* __restrict__ ncnt, int* __restrict__ pk3, int NBC, int n) {
    __shared__ int h4[1024];      // [node256][srcgrp4] histogram
    __shared__ int base4[1024];   // scatter cursors
    __shared__ int pb_s[256];     // padded base slot per node
    __shared__ int wsum_s[4];
    __shared__ int totpad_s;
    int tid = threadIdx.x;
    int B = blockIdx.x;
    int fill = curG[B * 16];
    if (fill > CAPC) {            // overflow (adversarial): flag for slow path
        if (tid < 16) fcnt[B * 16 + tid] = -1;
        return;
    }
    h4[tid] = 0;
    __syncthreads();
    size_t s0 = (size_t)B * CAPC;
    int vreg[CAPC / THR];         // fully unrolled -> registers
#pragma unroll
    for (int k = 0; k < CAPC / THR; k++) {
        int i = k * THR + tid;
        if (i < fill) {
            int p = pk2[s0 + i];
            vreg[k] = p;
            atomicAdd(&h4[(((((unsigned)p) >> 20) & 255) << 2) | ((p >> 15) & 3)], 1);
        }
    }
    __syncthreads();
    int incl = 0, pc = 0, cn = 0;
    if (tid < 256) {              // padded (mult-of-8) prefix over 256 nodes
        cn = h4[tid * 4] + h4[tid * 4 + 1] + h4[tid * 4 + 2] + h4[tid * 4 + 3];
        pc = (cn + 7) >> 3;
        incl = pc;
#pragma unroll
        for (int d = 1; d < 64; d <<= 1) {
            int y = __shfl_up(incl, d);
            if ((tid & 63) >= d) incl += y;
        }
        if ((tid & 63) == 63) wsum_s[tid >> 6] = incl;
    }
    __syncthreads();
    if (tid < 256) {
        int w = tid >> 6, woff = 0;
        for (int j = 0; j < w; j++) woff += wsum_s[j];
        int excl = incl - pc + woff;
        pb_s[tid] = excl << 3;
        if (tid == 255) totpad_s = (excl + pc) << 3;
    }
    __syncthreads();
    int totpad = totpad_s;
    if (totpad > CAPC) {          // pads wouldn't fit: flag (never for this input)
        if (tid < 16) fcnt[B * 16 + tid] = -1;
        return;
    }
    if (tid < 16) {
        int fs = pb_s[tid * 16];
        int fe = (tid == 15) ? totpad : pb_s[(tid + 1) * 16];
        fstart[B * 16 + tid] = (int)(s0 + fs);
        fcnt[B * 16 + tid] = fe - fs;
    }
    if (tid < 256) {
        int nd = B * 256 + tid;
        if (nd < n) ncnt[nd] = cn;
    }
    {   // scatter cursors: pb + within-node src-group prefix
        int nd = tid >> 2, g = tid & 3;
        int off = 0;
#pragma unroll
        for (int gg = 0; gg < 3; gg++) if (gg < g) off += h4[(nd << 2) | gg];
        base4[tid] = pb_s[nd] + off;
    }
    __syncthreads();
#pragma unroll
    for (int k = 0; k < CAPC / THR; k++) {
        int i = k * THR + tid;
        if (i < fill) {
            int p = vreg[k];
            int bin = (((((unsigned)p) >> 20) & 255) << 2) | ((p >> 15) & 3);
            int pos = atomicAdd(&base4[bin], 1);
            // keep src (bits 0..19) + node-WITHIN-fine (d&15, p bits 20..23) in 28..31
            pk3[s0 + pos] = (p & SRC20) | (((((unsigned)p) >> 20) & 15) << 28);
        }
    }
    if (tid < 256) {              // write pad sentinels (disjoint slots, no barrier)
        int pc8 = pc << 3;
        int padw = n | ((tid & 15) << 28);   // sentinel src + node-within-fine tag
        for (int k2 = cn; k2 < pc8; k2++)
            pk3[s0 + pb_s[tid] + k2] = padw;
    }
}

// ---------- FUSED: 2-deep pipelined f16 gather over padded runs + f16 MFMA ----------
__global__ __launch_bounds__(256) void k_agg_gemm(
        const unsigned short* __restrict__ xb, const int* __restrict__ pk3,
        const int* __restrict__ fstart, const int* __restrict__ fcnt,
        const int* __restrict__ ncnt,
        const unsigned short* __restrict__ wfrag,
        const float* __restrict__ b1, const float* __restrict__ W2l,
        const float* __restrict__ W2r,
        float* __restrict__ sarr, float* __restrict__ tarr,
        float* __restrict__ invdeg, int n,
        const int* __restrict__ idx, int E) {
    __shared__ int srcb[CAP];
    __shared__ int pbase_s[16];
    __shared__ int rcnt_s[16];
    __shared__ float rinv_s[16];
    __shared__ unsigned short aggh[16 * ASTH];   // f16 mean-agg rows
    __shared__ float sred[4 * 16], tred[4 * 16];
    __shared__ int is64_s;

    int tid = threadIdx.x;
    int b = blockIdx.x;
    int grp = tid >> 4, l = tid & 15;
    int node = b * 16 + grp;
    int m = fcnt[b];
    const char* xB = (const char*)xb;
    int sub = (l >> 3) & 1;                  // edge parity within the pair
    size_t qo = (size_t)(l & 7) << 4;        // 16B feature chunk (feats (l&7)*8..+7)

    if (m >= 0) {
        if (tid < 16) {           // per-node metadata: padded prefix within the span
            int nd = b * 16 + tid;
            int cn = (nd < n) ? ncnt[nd] : 0;
            int pc = (cn + 7) >> 3;
            int incl = pc;
#pragma unroll
            for (int d = 1; d < 16; d <<= 1) {
                int y = __shfl_up(incl, d, 16);
                if (tid >= d) incl += y;
            }
            pbase_s[tid] = (incl - pc) << 3;
            rcnt_s[tid] = cn;
            float iv = 1.0f / (float)(cn < 1 ? 1 : cn);
            rinv_s[tid] = iv;
            if (nd < n) invdeg[nd] = iv;
        }
        if (m <= CAP) {
            int ebeg = fstart[b];
            for (int i = tid; i < m; i += 256)
                srcb[i] = __builtin_nontemporal_load(pk3 + ebeg + i);
            __syncthreads();
            int cn = rcnt_s[grp];
            int pc8 = ((cn + 7) >> 3) << 3;       // padded: no tail, no predication
            int s0 = pbase_s[grp];
            h2 a0 = {0, 0}, a1 = {0, 0}, a2 = {0, 0}, a3 = {0, 0};
            if (pc8 > 0) {
                // ---- 2-deep software pipeline: issue next 4 loads, THEN accumulate
                int j0 = srcb[s0 + 0 + sub] & SRCMASK;
                int j1 = srcb[s0 + 2 + sub] & SRCMASK;
                int j2 = srcb[s0 + 4 + sub] & SRCMASK;
                int j3 = srcb[s0 + 6 + sub] & SRCMASK;
                uint4 v0 = *(const uint4*)(xB + ((size_t)j0 << 7) + qo);
                uint4 v1 = *(const uint4*)(xB + ((size_t)j1 << 7) + qo);
                uint4 v2 = *(const uint4*)(xB + ((size_t)j2 << 7) + qo);
                uint4 v3 = *(const uint4*)(xB + ((size_t)j3 << 7) + qo);
                for (int e = 8; e < pc8; e += 8) {
                    int k0 = srcb[s0 + e + 0 + sub] & SRCMASK;
                    int k1 = srcb[s0 + e + 2 + sub] & SRCMASK;
                    int k2 = srcb[s0 + e + 4 + sub] & SRCMASK;
                    int k3 = srcb[s0 + e + 6 + sub] & SRCMASK;
                    uint4 w0 = *(const uint4*)(xB + ((size_t)k0 << 7) + qo);
                    uint4 w1 = *(const uint4*)(xB + ((size_t)k1 << 7) + qo);
                    uint4 w2 = *(const uint4*)(xB + ((size_t)k2 << 7) + qo);
                    uint4 w3 = *(const uint4*)(xB + ((size_t)k3 << 7) + qo);
                    a0 = a0 + (bitsh2(v0.x) + bitsh2(v1.x)) + (bitsh2(v2.x) + bitsh2(v3.x));
                    a1 = a1 + (bitsh2(v0.y) + bitsh2(v1.y)) + (bitsh2(v2.y) + bitsh2(v3.y));
                    a2 = a2 + (bitsh2(v0.z) + bitsh2(v1.z)) + (bitsh2(v2.z) + bitsh2(v3.z));
                    a3 = a3 + (bitsh2(v0.w) + bitsh2(v1.w)) + (bitsh2(v2.w) + bitsh2(v3.w));
                    v0 = w0; v1 = w1; v2 = w2; v3 = w3;
                }
                a0 = a0 + (bitsh2(v0.x) + bitsh2(v1.x)) + (bitsh2(v2.x) + bitsh2(v3.x));
                a1 = a1 + (bitsh2(v0.y) + bitsh2(v1.y)) + (bitsh2(v2.y) + bitsh2(v3.y));
                a2 = a2 + (bitsh2(v0.z) + bitsh2(v1.z)) + (bitsh2(v2.z) + bitsh2(v3.z));
                a3 = a3 + (bitsh2(v0.w) + bitsh2(v1.w)) + (bitsh2(v2.w) + bitsh2(v3.w));
            }
            // merge the two parity lanes (l ^ 8) then mean-scale in f32
            a0 = a0 + bitsh2((unsigned)__shfl_xor((int)h2bits(a0), 8));
            a1 = a1 + bitsh2((unsigned)__shfl_xor((int)h2bits(a1), 8));
            a2 = a2 + bitsh2((unsigned)__shfl_xor((int)h2bits(a2), 8));
            a3 = a3 + bitsh2((unsigned)__shfl_xor((int)h2bits(a3), 8));
            float inv = rinv_s[grp];
            f32x2 g0 = __builtin_convertvector(a0, f32x2) * inv;
            f32x2 g1 = __builtin_convertvector(a1, f32x2) * inv;
            f32x2 g2 = __builtin_convertvector(a2, f32x2) * inv;
            f32x2 g3 = __builtin_convertvector(a3, f32x2) * inv;
            if (l < 8) {
                union { h2 h[4]; uint4 u; } ou;
                ou.h[0] = __builtin_convertvector(g0, h2);
                ou.h[1] = __builtin_convertvector(g1, h2);
                ou.h[2] = __builtin_convertvector(g2, h2);
                ou.h[3] = __builtin_convertvector(g3, h2);
                *(uint4*)(aggh + grp * ASTH + l * 8) = ou.u;
            }
        } else {
            // rare big bucket: per-group padded walk straight from global
            __syncthreads();
            int cn = rcnt_s[grp];
            int pc8 = ((cn + 7) >> 3) << 3;
            int base = fstart[b] + pbase_s[grp];
            h2 a0 = {0, 0}, a1 = {0, 0}, a2 = {0, 0}, a3 = {0, 0};
            for (int e = 0; e < pc8; e += 8) {
#pragma unroll
                for (int k = 0; k < 8; k++) {
                    int j = __builtin_nontemporal_load(pk3 + base + e + k) & SRCMASK;
                    uint4 v = *(const uint4*)(xB + ((size_t)j << 7) + qo);
                    a0 = a0 + bitsh2(v.x); a1 = a1 + bitsh2(v.y);
                    a2 = a2 + bitsh2(v.z); a3 = a3 + bitsh2(v.w);
                }
            }
            float inv = rinv_s[grp];       // all 16 lanes scanned all edges: no merge
            f32x2 g0 = __builtin_convertvector(a0, f32x2) * inv;
            f32x2 g1 = __builtin_convertvector(a1, f32x2) * inv;
            f32x2 g2 = __builtin_convertvector(a2, f32x2) * inv;
            f32x2 g3 = __builtin_convertvector(a3, f32x2) * inv;
            if (l < 8) {
                union { h2 h[4]; uint4 u; } ou;
                ou.h[0] = __builtin_convertvector(g0, h2);
                ou.h[1] = __builtin_convertvector(g1, h2);
                ou.h[2] = __builtin_convertvector(g2, h2);
                ou.h[3] = __builtin_convertvector(g3, h2);
                *(uint4*)(aggh + grp * ASTH + l * 8) = ou.u;
            }
        }
    } else {
        // flagged (span overflow): correct-but-slow direct scan of idx
        if (tid < 64) {
            int v = idx[2 * tid + 1];
            unsigned long long bl = __ballot(v != 0);
            if (tid == 0) is64_s = (bl == 0ULL) ? 1 : 0;
        }
        __syncthreads();
        int is64 = is64_s;
        h2 a0 = {0, 0}, a1 = {0, 0}, a2 = {0, 0}, a3 = {0, 0};
        int cnt = 0;
        if (node < n) {
            for (long e = 0; e < E; e++) {
                int d = is64 ? idx[2L * E + 2 * e] : idx[(long)E + e];
                if (d == node) {
                    int s = is64 ? idx[2 * e] : idx[e];
                    cnt++;
                    uint4 v = *(const uint4*)(xB + ((size_t)s << 7) + qo);
                    a0 = a0 + bitsh2(v.x); a1 = a1 + bitsh2(v.y);
                    a2 = a2 + bitsh2(v.z); a3 = a3 + bitsh2(v.w);
                }
            }
        }
        float iv = 1.0f / (float)(cnt < 1 ? 1 : cnt);
        if (l == 0 && node < n) invdeg[node] = iv;
        f32x2 g0 = __builtin_convertvector(a0, f32x2) * iv;
        f32x2 g1 = __builtin_convertvector(a1, f32x2) * iv;
        f32x2 g2 = __builtin_convertvector(a2, f32x2) * iv;
        f32x2 g3 = __builtin_convertvector(a3, f32x2) * iv;
        if (l < 8) {
            union { h2 h[4]; uint4 u; } ou;
            ou.h[0] = __builtin_convertvector(g0, h2);
            ou.h[1] = __builtin_convertvector(g1, h2);
            ou.h[2] = __builtin_convertvector(g2, h2);
            ou.h[3] = __builtin_convertvector(g3, h2);
            *(uint4*)(aggh + grp * ASTH + l * 8) = ou.u;
        }
    }
    __syncthreads();

    // ---- epilogue: f16 MFMA + layer-2 partials ----
    int wave = tid >> 6;
    int lane = tid & 63;
    int nloc = lane & 15, quad = lane >> 4;

    const unsigned short* ar = aggh + nloc * ASTH + quad * 8;
    half8 aA0 = *(const half8*)ar;
    half8 aA1 = *(const half8*)(ar + 32);
    int node_a = b * 16 + nloc;
    int nc = node_a < n ? node_a : (n - 1);
    const unsigned short* xr = xb + (size_t)nc * 64;
    half8 aX0 = *(const half8*)(xr + quad * 8);
    half8 aX1 = *(const half8*)(xr + 32 + quad * 8);

    const half8 bL0 = *(const half8*)(wfrag + ((size_t)((0 * 4 + wave) * 2 + 0) * 64 + lane) * 8);
    const half8 bL1 = *(const half8*)(wfrag + ((size_t)((0 * 4 + wave) * 2 + 1) * 64 + lane) * 8);
    const half8 bR0 = *(const half8*)(wfrag + ((size_t)((1 * 4 + wave) * 2 + 0) * 64 + lane) * 8);
    const half8 bR1 = *(const half8*)(wfrag + ((size_t)((1 * 4 + wave) * 2 + 1) * 64 + lane) * 8);

    f32x4 acc = (f32x4){0.f, 0.f, 0.f, 0.f};
    acc = __builtin_amdgcn_mfma_f32_16x16x32_f16(aA0, bL0, acc, 0, 0, 0);
    acc = __builtin_amdgcn_mfma_f32_16x16x32_f16(aA1, bL1, acc, 0, 0, 0);
    acc = __builtin_amdgcn_mfma_f32_16x16x32_f16(aX0, bR0, acc, 0, 0, 0);
    acc = __builtin_amdgcn_mfma_f32_16x16x32_f16(aX1, bR1, acc, 0, 0, 0);

    int j = wave * 16 + nloc;
    float b1v = b1[j], w2lv = W2l[j], w2rv = W2r[j];
    float sp[4], tp[4];
#pragma unroll
    for (int r = 0; r < 4; r++) {
        float h = fmaxf(acc[r] + b1v, 0.f);
        sp[r] = h * w2lv;
        tp[r] = h * w2rv;
    }
#pragma unroll
    for (int mm = 1; mm < 16; mm <<= 1) {
#pragma unroll
        for (int r = 0; r < 4; r++) {
            sp[r] += __shfl_xor(sp[r], mm);
            tp[r] += __shfl_xor(tp[r], mm);
        }
    }
    if (nloc == 0) {
#pragma unroll
        for (int r = 0; r < 4; r++) {
            sred[wave * 16 + quad * 4 + r] = sp[r];
            tred[wave * 16 + quad * 4 + r] = tp[r];
        }
    }
    __syncthreads();
    if (tid < 16) {
        int nd = b * 16 + tid;
        if (nd < n) {
            sarr[nd] = sred[tid] + sred[16 + tid] + sred[32 + tid] + sred[48 + tid];
            tarr[nd] = tred[tid] + tred[16 + tid] + tred[32 + tid] + tred[48 + tid];
        }
    }
}

// ---------- per-fine-bucket layer-2 mean aggregation + output ----------
__global__ __launch_bounds__(256) void k_final2(const int* __restrict__ pk3,
        const int* __restrict__ fstart, const int* __restrict__ fcnt,
        const float* __restrict__ sarr, const float* __restrict__ tarr,
        const float* __restrict__ invdeg, const float* __restrict__ b2,
        float* __restrict__ out, int n,
        const int* __restrict__ idx, int E) {
    __shared__ float accr[16 * 8];
    __shared__ int is64_s;
    int tid = threadIdx.x;
    int b = blockIdx.x;
    int m = fcnt[b];
    if (tid < 128) accr[tid] = 0.f;
    __syncthreads();
    if (m >= 0) {
        int ebeg = fstart[b];
        int rep = tid & 7;
        int i = ebeg + tid, end = ebeg + m;
        if (i < end) {
            // 2-deep pipeline: issue next pk3 load before the dependent sarr chase
            int p = __builtin_nontemporal_load(pk3 + i);
            for (; i + 256 < end; i += 256) {
                int pn = __builtin_nontemporal_load(pk3 + i + 256);
                float s = sarr[p & SRCMASK];        // pads hit sarr[n] == 0
                atomicAdd(&accr[(((unsigned)p) >> 28) * 8 + rep], s);
                p = pn;
            }
            float s = sarr[p & SRCMASK];
            atomicAdd(&accr[(((unsigned)p) >> 28) * 8 + rep], s);
        }
        __syncthreads();
        if (tid < 16) {
            int node = b * 16 + tid;
            if (node < n) {
                float a = 0.f;
#pragma unroll
                for (int r = 0; r < 8; r++) a += accr[tid * 8 + r];
                out[node] = a * invdeg[node] + b2[0] + tarr[node];
            }
        }
    } else {
        // flagged: slow direct scan
        if (tid < 64) {
            int v = idx[2 * tid + 1];
            unsigned long long bl = __ballot(v != 0);
            if (tid == 0) is64_s = (bl == 0ULL) ? 1 : 0;
        }
        __syncthreads();
        int is64 = is64_s;
        if (tid < 16) {
            int node = b * 16 + tid;
            if (node < n) {
                float a = 0.f;
                for (long e = 0; e < E; e++) {
                    int d = is64 ? idx[2L * E + 2 * e] : idx[(long)E + e];
                    if (d == node) {
                        int s = is64 ? idx[2 * e] : idx[e];
                        a += sarr[s];
                    }
                }
                out[node] = a * invdeg[node] + b2[0] + tarr[node];
            }
        }
    }
}

extern "C" void kernel_launch(void* const* d_in, const int* in_sizes, int n_in,
                              void* d_out, int out_size, void* d_ws, size_t ws_size,
                              hipStream_t stream) {
    const float* x   = (const float*)d_in[0];
    const int*   idx = (const int*)d_in[1];
    const float* W1l = (const float*)d_in[2];
    const float* b1  = (const float*)d_in[3];
    const float* W1r = (const float*)d_in[4];
    const float* W2l = (const float*)d_in[5];
    const float* b2  = (const float*)d_in[6];
    const float* W2r = (const float*)d_in[7];
    float* out = (float*)d_out;

    const int n = in_sizes[0] / 64;       // 100000
    const int E = in_sizes[1] / 2;        // 1600000
    const int NBC = (n + 255) >> BSHC;    // coarse buckets (256 nodes)
    const int NBF = NBC * 16;             // fine buckets (16 nodes)

    char* ws = (char*)d_ws;
    size_t off = 0;
    auto carve = [&](size_t bytes) {
        void* p = ws + off;
        off = (off + bytes + 255) & ~(size_t)255;
        return p;
    };
    float* sarr    = (float*)carve((size_t)(n + 1) * 4);    // +1: zero sentinel
    float* tarr    = (float*)carve((size_t)n * 4);
    float* invdeg  = (float*)carve((size_t)n * 4);
    int*   ncnt    = (int*)  carve((size_t)n * 4);
    int*   curG    = (int*)  carve((size_t)NBC * 64);        // 64B-padded cursors
    int*   fstart  = (int*)  carve((size_t)NBF * 4);
    int*   fcnt    = (int*)  carve((size_t)NBF * 4);
    unsigned short* wfrag = (unsigned short*)carve(16 * 64 * 8 * 2);
    int*   pk2  = (int*)carve((size_t)NBC * CAPC * 4);
    int*   pk3  = (int*)carve((size_t)NBC * CAPC * 4);
    unsigned short* xbu = (unsigned short*)carve((size_t)(n + 1) * 128);  // +1: zero row
    (void)ws_size; (void)n_in; (void)out_size;

    const int total8 = n * 8;
    const int xblocks = (total8 + THR - 1) / THR;
    const int nbs = (E + EPB - 1) / EPB;
    const size_t dynLds = (size_t)EPB * 6 + (size_t)NBC * 12;

    hipMemsetAsync(curG, 0, (size_t)NBC * 64, stream);
    k_prep_all<<<nbs + xblocks + 1, THR, dynLds, stream>>>(
        idx, curG, pk2, E, NBC, nbs, x, (unsigned*)xbu, total8, n, sarr, W1l, W1r, wfrag, xblocks);
    k_refine<<<NBC, THR, 0, stream>>>(pk2, curG, fstart, fcnt, ncnt, pk3, NBC, n);
    k_agg_gemm<<<NBF, BS, 0, stream>>>(xbu, pk3, fstart, fcnt, ncnt, wfrag, b1, W2l, W2r,
                                       sarr, tarr, invdeg, n, idx, E);
    k_final2<<<NBF, BS, 0, stream>>>(pk3, fstart, fcnt, sarr, tarr, invdeg, b2,
                                     out, n, idx, E);
}